// Round 1
// baseline (1201.791 us; speedup 1.0000x reference)
//
#include <hip/hip_runtime.h>

#define NN 50000
#define EE 800000
#define MM 3
#define HH 2
#define IND 128
#define HIDD 64
#define HEADD 32
#define OUTD 16
#define ATTD 128

__device__ __forceinline__ float lrelu(float v) { return v > 0.f ? v : 0.1f * v; }

// ---------------- degree count ----------------
__global__ void k_deg(const int* __restrict__ ei, int* __restrict__ deg) {
    int t = blockIdx.x * 256 + threadIdx.x;
    if (t >= MM * EE) return;
    int m = t / EE, e = t - m * EE;
    int dst = ei[(size_t)m * 2 * EE + EE + e];
    atomicAdd(&deg[m * NN + dst], 1);
}

// ---------------- exclusive scan (one block per metapath) ----------------
__global__ void k_scan(const int* __restrict__ deg, int* __restrict__ ofs) {
    __shared__ int buf[1024];
    __shared__ int carry_s;
    const int m = blockIdx.x;
    const int* d = deg + (size_t)m * NN;
    int* o = ofs + (size_t)m * (NN + 1);
    const int tid = threadIdx.x;
    if (tid == 0) carry_s = 0;
    __syncthreads();
    for (int base = 0; base < NN; base += 1024) {
        int i = base + tid;
        int v = (i < NN) ? d[i] : 0;
        buf[tid] = v;
        __syncthreads();
        for (int s = 1; s < 1024; s <<= 1) {
            int t = (tid >= s) ? buf[tid - s] : 0;
            __syncthreads();
            buf[tid] += t;
            __syncthreads();
        }
        int carry = carry_s;
        if (i < NN) o[i] = carry + buf[tid] - v;   // exclusive
        __syncthreads();
        if (tid == 0) carry_s = carry + buf[1023];
        __syncthreads();
    }
    if (tid == 0) o[NN] = carry_s;
}

// ---------------- rs = rsqrt(deg+1) ----------------
__global__ void k_rs(const int* __restrict__ ofs, float* __restrict__ rs) {
    int t = blockIdx.x * 256 + threadIdx.x;
    if (t >= MM * NN) return;
    int m = t / NN, n = t - m * NN;
    const int* o = ofs + (size_t)m * (NN + 1);
    int cnt = o[n + 1] - o[n];
    rs[t] = rsqrtf((float)(cnt + 1));
}

// ---------------- CSR fill (backward, reuses deg as cursor) ----------------
__global__ void k_fill(const int* __restrict__ ei, int* __restrict__ deg,
                       const int* __restrict__ ofs, int* __restrict__ sorted) {
    int t = blockIdx.x * 256 + threadIdx.x;
    if (t >= MM * EE) return;
    int m = t / EE, e = t - m * EE;
    int src = ei[(size_t)m * 2 * EE + e];
    int dst = ei[(size_t)m * 2 * EE + EE + e];
    int old = atomicSub(&deg[m * NN + dst], 1);
    int pos = ofs[(size_t)m * (NN + 1) + dst] + old - 1;
    sorted[(size_t)m * EE + pos] = src;
}

// ---------------- shared GEMM tile core: in_tile [64][68], w [k][OD] ----------------
template <int OD>
__device__ __forceinline__ void gemm_tile_compute(const float* lds_in, const float* lds_w,
                                                  float (*acc)[4], int tid) {
    constexpr int CG = OD / 4;
    constexpr int NP = 256 / CG;
    constexpr int NPASS = 64 / NP;
    const int cg = tid % CG;
    const int nid = tid / CG;
    for (int k0 = 0; k0 < 64; k0 += 8) {
        float4 w[8];
#pragma unroll
        for (int j = 0; j < 8; j++) w[j] = *(const float4*)&lds_w[(k0 + j) * OD + cg * 4];
#pragma unroll
        for (int p = 0; p < NPASS; p++) {
            const float* xr = &lds_in[(nid + p * NP) * 68 + k0];
            float4 xa = *(const float4*)xr;
            float4 xb = *(const float4*)(xr + 4);
            float xs[8] = {xa.x, xa.y, xa.z, xa.w, xb.x, xb.y, xb.z, xb.w};
#pragma unroll
            for (int j = 0; j < 8; j++) {
                acc[p][0] = fmaf(xs[j], w[j].x, acc[p][0]);
                acc[p][1] = fmaf(xs[j], w[j].y, acc[p][1]);
                acc[p][2] = fmaf(xs[j], w[j].z, acc[p][2]);
                acc[p][3] = fmaf(xs[j], w[j].w, acc[p][3]);
            }
        }
    }
}

// ---------------- generic per-head GEMM: out = act(in @ W + b) ----------------
template <int KD, int OD, int ACT, bool HAS_B>
__global__ __launch_bounds__(256) void k_gemm(const float* __restrict__ in, long in_sh,
                                              const float* __restrict__ W,
                                              const float* __restrict__ B,
                                              float* __restrict__ out, long out_sh) {
    __shared__ float lds_in[64 * 68];
    __shared__ float lds_w[KD * OD];
    __shared__ float lds_b[OD];
    const int hd = blockIdx.y, tid = threadIdx.x;
    const int nbase = blockIdx.x * 64;
    const float* gin = in + (long)hd * in_sh;
    const float* gw = W + (long)hd * KD * OD;

    for (int qq = tid; qq < KD * OD / 4; qq += 256)
        ((float4*)lds_w)[qq] = ((const float4*)gw)[qq];
    if (tid < OD) lds_b[tid] = HAS_B ? B[(long)hd * OD + tid] : 0.f;

    constexpr int CG = OD / 4, NP = 256 / CG, NPASS = 64 / NP;
    float acc[NPASS][4];
#pragma unroll
    for (int p = 0; p < NPASS; p++) acc[p][0] = acc[p][1] = acc[p][2] = acc[p][3] = 0.f;

    for (int ks = 0; ks < KD; ks += 64) {
        __syncthreads();   // guards w/bias load on iter0, WAR on in_tile after
        for (int qq = tid; qq < 64 * 16; qq += 256) {
            int node = qq >> 4, k4 = qq & 15;
            int ng = nbase + node;
            float4 v = make_float4(0.f, 0.f, 0.f, 0.f);
            if (ng < NN) v = *(const float4*)&gin[(long)ng * KD + ks + k4 * 4];
            *(float4*)&lds_in[node * 68 + k4 * 4] = v;
        }
        __syncthreads();
        gemm_tile_compute<OD>(lds_in, lds_w + ks * OD, acc, tid);
    }

    const int cg = tid % CG, nid = tid / CG;
    float* gout = out + (long)hd * out_sh;
#pragma unroll
    for (int p = 0; p < NPASS; p++) {
        int ng = nbase + nid + p * NP;
        if (ng < NN) {
            float4 r;
            r.x = acc[p][0] + lds_b[cg * 4 + 0];
            r.y = acc[p][1] + lds_b[cg * 4 + 1];
            r.z = acc[p][2] + lds_b[cg * 4 + 2];
            r.w = acc[p][3] + lds_b[cg * 4 + 3];
            if (ACT == 1) { r.x = lrelu(r.x); r.y = lrelu(r.y); r.z = lrelu(r.z); r.w = lrelu(r.w); }
            *(float4*)&gout[(long)ng * OD + cg * 4] = r;
        }
    }
}

// ---------------- CSR gather: one wave per dst, lanes = (edge-parity, 128ch/4) ----------------
__global__ __launch_bounds__(256) void k_gather(const int* __restrict__ sorted,
                                                const int* __restrict__ ofs,
                                                const float* __restrict__ rs,
                                                const float* __restrict__ xw,
                                                float* __restrict__ gg) {
    const int tid = threadIdx.x;
    const int dst = blockIdx.x * 4 + (tid >> 6);
    if (dst >= NN) return;
    const int lane = tid & 63;
    const int p = lane >> 5;
    const int cg = lane & 31;
    const size_t rowbase = (size_t)(cg >> 4) * NN * 16;  // head plane, float4 units
    const int c4 = cg & 15;
    const float4* x4 = (const float4*)xw;
    int beg = ofs[dst], end = ofs[dst + 1];
    float4 acc = make_float4(0.f, 0.f, 0.f, 0.f);
    for (int j = beg + p; j < end; j += 2) {
        int src = sorted[j];
        float c = rs[src];
        float4 v = x4[rowbase + (size_t)src * 16 + c4];
        acc.x = fmaf(c, v.x, acc.x);
        acc.y = fmaf(c, v.y, acc.y);
        acc.z = fmaf(c, v.z, acc.z);
        acc.w = fmaf(c, v.w, acc.w);
    }
    acc.x += __shfl_down(acc.x, 32);
    acc.y += __shfl_down(acc.y, 32);
    acc.z += __shfl_down(acc.z, 32);
    acc.w += __shfl_down(acc.w, 32);
    if (p == 0) {
        float rsd = rs[dst];
        float4 r = make_float4(acc.x * rsd, acc.y * rsd, acc.z * rsd, acc.w * rsd);
        ((float4*)gg)[rowbase + (size_t)dst * 16 + c4] = r;
    }
}

// ---------------- post: lrelu(agg + xw/deg + b_conv) @ W_dec + b_dec -> z ----------------
__global__ __launch_bounds__(256) void k_post(const float* __restrict__ gg,
                                              const float* __restrict__ xw,
                                              const int* __restrict__ ofs,
                                              const float* __restrict__ bconv,
                                              const float* __restrict__ Wdec,
                                              const float* __restrict__ bdec,
                                              float* __restrict__ zout) {
    constexpr int KD = 64, OD = 32;
    __shared__ float lds_in[64 * 68];
    __shared__ float lds_w[KD * OD];
    __shared__ float lds_b[OD];
    const int hd = blockIdx.y, tid = threadIdx.x;
    const int nbase = blockIdx.x * 64;

    for (int qq = tid; qq < 64 * 16; qq += 256) {
        int node = qq >> 4, k4 = qq & 15;
        int ng = nbase + node;
        float4 v = make_float4(0.f, 0.f, 0.f, 0.f);
        if (ng < NN) {
            int cnt = ofs[ng + 1] - ofs[ng];
            float idg = 1.f / (float)(cnt + 1);
            float4 a = *(const float4*)&gg[((size_t)hd * NN + ng) * 64 + k4 * 4];
            float4 xv = *(const float4*)&xw[((size_t)hd * NN + ng) * 64 + k4 * 4];
            float4 bb = *(const float4*)&bconv[hd * 64 + k4 * 4];
            v.x = lrelu(fmaf(xv.x, idg, a.x) + bb.x);
            v.y = lrelu(fmaf(xv.y, idg, a.y) + bb.y);
            v.z = lrelu(fmaf(xv.z, idg, a.z) + bb.z);
            v.w = lrelu(fmaf(xv.w, idg, a.w) + bb.w);
        }
        *(float4*)&lds_in[node * 68 + k4 * 4] = v;
    }
    for (int qq = tid; qq < KD * OD / 4; qq += 256)
        ((float4*)lds_w)[qq] = ((const float4*)(Wdec + (size_t)hd * KD * OD))[qq];
    if (tid < OD) lds_b[tid] = bdec[hd * OD + tid];
    __syncthreads();

    constexpr int CG = OD / 4, NP = 256 / CG, NPASS = 64 / NP;
    float acc[NPASS][4];
#pragma unroll
    for (int p = 0; p < NPASS; p++) acc[p][0] = acc[p][1] = acc[p][2] = acc[p][3] = 0.f;
    gemm_tile_compute<OD>(lds_in, lds_w, acc, tid);

    const int cg = tid % CG, nid = tid / CG;
#pragma unroll
    for (int p = 0; p < NPASS; p++) {
        int ng = nbase + nid + p * NP;
        if (ng < NN) {
            float4 r;
            r.x = acc[p][0] + lds_b[cg * 4 + 0];
            r.y = acc[p][1] + lds_b[cg * 4 + 1];
            r.z = acc[p][2] + lds_b[cg * 4 + 2];
            r.w = acc[p][3] + lds_b[cg * 4 + 3];
            *(float4*)&zout[(size_t)ng * 64 + hd * 32 + cg * 4] = r;
        }
    }
}

// ---------------- semantic attention scores ----------------
__global__ __launch_bounds__(256) void k_score(const float* __restrict__ z,
                                               const float* __restrict__ Ws,
                                               const float* __restrict__ bs,
                                               const float* __restrict__ qv,
                                               float* __restrict__ score) {
    constexpr int KD = 64, OD = 128;
    __shared__ float lds_in[64 * 68];
    __shared__ float lds_w[KD * OD];
    __shared__ float lds_b[OD];
    const int m = blockIdx.y, tid = threadIdx.x;
    const int nbase = blockIdx.x * 64;
    const float* gin = z + (size_t)m * NN * 64;

    for (int qq = tid; qq < 64 * 16; qq += 256) {
        int node = qq >> 4, k4 = qq & 15;
        int ng = nbase + node;
        float4 v = make_float4(0.f, 0.f, 0.f, 0.f);
        if (ng < NN) v = *(const float4*)&gin[(size_t)ng * 64 + k4 * 4];
        *(float4*)&lds_in[node * 68 + k4 * 4] = v;
    }
    for (int qq = tid; qq < KD * OD / 4; qq += 256)
        ((float4*)lds_w)[qq] = ((const float4*)Ws)[qq];
    if (tid < OD) lds_b[tid] = bs[tid];
    __syncthreads();

    constexpr int CG = 32, NP = 8, NPASS = 8;
    float acc[NPASS][4];
#pragma unroll
    for (int p = 0; p < NPASS; p++) acc[p][0] = acc[p][1] = acc[p][2] = acc[p][3] = 0.f;
    gemm_tile_compute<OD>(lds_in, lds_w, acc, tid);

    const int cg = tid % CG, nid = tid / CG;
    float4 qf = *(const float4*)&qv[cg * 4];
    float s = 0.f;
#pragma unroll
    for (int p = 0; p < NPASS; p++) {
        int ng = nbase + nid + p * NP;
        if (ng < NN) {
            s += tanhf(acc[p][0] + lds_b[cg * 4 + 0]) * qf.x;
            s += tanhf(acc[p][1] + lds_b[cg * 4 + 1]) * qf.y;
            s += tanhf(acc[p][2] + lds_b[cg * 4 + 2]) * qf.z;
            s += tanhf(acc[p][3] + lds_b[cg * 4 + 3]) * qf.w;
        }
    }
    for (int off = 32; off > 0; off >>= 1) s += __shfl_down(s, off);
    if ((tid & 63) == 0) atomicAdd(&score[m], s);
}

// ---------------- beta = softmax(score/N) ----------------
__global__ void k_beta(const float* __restrict__ score, float* __restrict__ beta_ws,
                       float* __restrict__ out) {
    if (threadIdx.x == 0) {
        float s0 = score[0] / (float)NN, s1 = score[1] / (float)NN, s2 = score[2] / (float)NN;
        float mx = fmaxf(s0, fmaxf(s1, s2));
        float e0 = expf(s0 - mx), e1 = expf(s1 - mx), e2 = expf(s2 - mx);
        float inv = 1.f / (e0 + e1 + e2);
        beta_ws[0] = e0 * inv; beta_ws[1] = e1 * inv; beta_ws[2] = e2 * inv;
        out[800000] = e0 * inv; out[800001] = e1 * inv; out[800002] = e2 * inv;
    }
}

// ---------------- output: log_softmax((beta . z) @ W_o + b_o) ----------------
__global__ __launch_bounds__(256) void k_out(const float* __restrict__ z,
                                             const float* __restrict__ beta,
                                             const float* __restrict__ Wo,
                                             const float* __restrict__ bo,
                                             float* __restrict__ out) {
    __shared__ float Zt[64 * 68];
    __shared__ float Wl[64 * 16];
    __shared__ float bl[16];
    const int tid = threadIdx.x, nbase = blockIdx.x * 64;
    float b0 = beta[0], b1 = beta[1], b2 = beta[2];
    for (int qq = tid; qq < 64 * 16; qq += 256) {
        int node = qq >> 4, k4 = qq & 15;
        int ng = nbase + node;
        float4 v = make_float4(0.f, 0.f, 0.f, 0.f);
        if (ng < NN) {
            float4 z0 = *(const float4*)&z[((size_t)0 * NN + ng) * 64 + k4 * 4];
            float4 z1 = *(const float4*)&z[((size_t)1 * NN + ng) * 64 + k4 * 4];
            float4 z2 = *(const float4*)&z[((size_t)2 * NN + ng) * 64 + k4 * 4];
            v.x = b0 * z0.x + b1 * z1.x + b2 * z2.x;
            v.y = b0 * z0.y + b1 * z1.y + b2 * z2.y;
            v.z = b0 * z0.z + b1 * z1.z + b2 * z2.z;
            v.w = b0 * z0.w + b1 * z1.w + b2 * z2.w;
        }
        *(float4*)&Zt[node * 68 + k4 * 4] = v;
    }
    for (int qq = tid; qq < 64 * 16 / 4; qq += 256)
        ((float4*)Wl)[qq] = ((const float4*)Wo)[qq];
    if (tid < 16) bl[tid] = bo[tid];
    __syncthreads();

    const int node = tid >> 2, cg = tid & 3;
    float4 a = make_float4(bl[cg * 4 + 0], bl[cg * 4 + 1], bl[cg * 4 + 2], bl[cg * 4 + 3]);
    for (int k = 0; k < 64; k++) {
        float zv = Zt[node * 68 + k];
        float4 w = *(const float4*)&Wl[k * 16 + cg * 4];
        a.x = fmaf(zv, w.x, a.x);
        a.y = fmaf(zv, w.y, a.y);
        a.z = fmaf(zv, w.z, a.z);
        a.w = fmaf(zv, w.w, a.w);
    }
    float mx = fmaxf(fmaxf(a.x, a.y), fmaxf(a.z, a.w));
    mx = fmaxf(mx, __shfl_xor(mx, 1));
    mx = fmaxf(mx, __shfl_xor(mx, 2));
    float sm = expf(a.x - mx) + expf(a.y - mx) + expf(a.z - mx) + expf(a.w - mx);
    sm += __shfl_xor(sm, 1);
    sm += __shfl_xor(sm, 2);
    float lse = mx + logf(sm);
    int ng = nbase + node;
    if (ng < NN) {
        float4 r = make_float4(a.x - lse, a.y - lse, a.z - lse, a.w - lse);
        *(float4*)&out[(size_t)ng * 16 + cg * 4] = r;
    }
}

extern "C" void kernel_launch(void* const* d_in, const int* in_sizes, int n_in,
                              void* d_out, int out_size, void* d_ws, size_t ws_size,
                              hipStream_t stream) {
    const float* x      = (const float*)d_in[0];
    const int*   ei     = (const int*)d_in[1];
    const float* W_enc  = (const float*)d_in[2];
    const float* b_enc  = (const float*)d_in[3];
    const float* W_conv = (const float*)d_in[4];
    const float* b_conv = (const float*)d_in[5];
    const float* W_dec  = (const float*)d_in[6];
    const float* b_dec  = (const float*)d_in[7];
    const float* W_s    = (const float*)d_in[8];
    const float* b_s    = (const float*)d_in[9];
    const float* qv     = (const float*)d_in[10];
    const float* W_o    = (const float*)d_in[11];
    const float* b_o    = (const float*)d_in[12];
    float* out = (float*)d_out;

    char* ws = (char*)d_ws;
    size_t off = 0;
    auto alloc = [&](size_t bytes) -> char* {
        char* p = ws + off;
        off = (off + bytes + 255) & ~(size_t)255;
        return p;
    };
    int*   deg_i   = (int*)alloc((size_t)MM * NN * 4);
    int*   row_ofs = (int*)alloc((size_t)MM * (NN + 1) * 4);
    float* rs      = (float*)alloc((size_t)MM * NN * 4);
    int*   sorted  = (int*)alloc((size_t)MM * EE * 4);
    float* score   = (float*)alloc(64);
    float* beta_ws = (float*)alloc(64);
    float* h_buf   = (float*)alloc((size_t)HH * NN * 64 * 4);
    float* xw_buf  = (float*)alloc((size_t)HH * NN * 64 * 4);
    float* z_buf   = (float*)alloc((size_t)MM * NN * 64 * 4);
    float* gg_buf  = h_buf;  // h dead after conv; reuse as gather output

    hipMemsetAsync(deg_i, 0, (size_t)MM * NN * 4, stream);
    hipMemsetAsync(score, 0, 16, stream);

    k_deg<<<(MM * EE + 255) / 256, 256, 0, stream>>>(ei, deg_i);
    k_scan<<<MM, 1024, 0, stream>>>(deg_i, row_ofs);
    k_rs<<<(MM * NN + 255) / 256, 256, 0, stream>>>(row_ofs, rs);
    k_fill<<<(MM * EE + 255) / 256, 256, 0, stream>>>(ei, deg_i, row_ofs, sorted);

    dim3 gh((NN + 63) / 64, HH);
    for (int m = 0; m < MM; m++) {
        k_gemm<IND, HIDD, 1, true><<<gh, 256, 0, stream>>>(
            x, 0L, W_enc + (size_t)m * HH * IND * HIDD, b_enc + (size_t)m * HH * HIDD,
            h_buf, (long)NN * 64);
        k_gemm<HIDD, HIDD, 0, false><<<gh, 256, 0, stream>>>(
            h_buf, (long)NN * 64, W_conv + (size_t)m * HH * HIDD * HIDD, nullptr,
            xw_buf, (long)NN * 64);
        k_gather<<<(NN + 3) / 4, 256, 0, stream>>>(
            sorted + (size_t)m * EE, row_ofs + (size_t)m * (NN + 1), rs + (size_t)m * NN,
            xw_buf, gg_buf);
        k_post<<<gh, 256, 0, stream>>>(
            gg_buf, xw_buf, row_ofs + (size_t)m * (NN + 1), b_conv + (size_t)m * HH * HIDD,
            W_dec + (size_t)m * HH * HIDD * HEADD, b_dec + (size_t)m * HH * HEADD,
            z_buf + (size_t)m * NN * 64);
    }
    dim3 gs((NN + 63) / 64, MM);
    k_score<<<gs, 256, 0, stream>>>(z_buf, W_s, b_s, qv, score);
    k_beta<<<1, 64, 0, stream>>>(score, beta_ws, out);
    k_out<<<(NN + 63) / 64, 256, 0, stream>>>(z_buf, beta_ws, W_o, b_o, out);
}

// Round 2
// 1197.137 us; speedup vs baseline: 1.0039x; 1.0039x over previous
//
#include <hip/hip_runtime.h>

#define NN 50000
#define EE 800000
#define MM 3
#define HH 2
#define IND 128
#define HIDD 64
#define HEADD 32
#define OUTD 16
#define ATTD 128

#define NPART 8
#define PSZ 6250          // NN / NPART
#define NSLICE 40
#define CHUNK4 5000       // (EE / NSLICE) / 4

__device__ __forceinline__ float lrelu(float v) { return v > 0.f ? v : 0.1f * v; }

__device__ __forceinline__ float fast_tanh(float x) {
    float ax = fabsf(x);
    float e = __expf(-2.0f * ax);
    float t = (1.0f - e) * __builtin_amdgcn_rcpf(1.0f + e);
    return copysignf(t, x);
}

// ---------------- degree count, XCD-partitioned by dst range ----------------
__global__ __launch_bounds__(256) void k_deg(const int* __restrict__ ei, int* __restrict__ deg) {
    const int m = blockIdx.y;
    const int part = blockIdx.x & 7;
    const int slice = blockIdx.x >> 3;
    const int lo = part * PSZ, hi = lo + PSZ;
    const int4* d4 = (const int4*)(ei + (size_t)m * 2 * EE + EE);
    int* dg = deg + m * NN;
    const int base = slice * CHUNK4;
    for (int q = base + threadIdx.x; q < base + CHUNK4; q += 256) {
        int4 v = d4[q];
        if (v.x >= lo && v.x < hi) atomicAdd(&dg[v.x], 1);
        if (v.y >= lo && v.y < hi) atomicAdd(&dg[v.y], 1);
        if (v.z >= lo && v.z < hi) atomicAdd(&dg[v.z], 1);
        if (v.w >= lo && v.w < hi) atomicAdd(&dg[v.w], 1);
    }
}

// ---------------- exclusive scan + fused rsqrt(deg+1), 1 block/metapath ----------------
__global__ __launch_bounds__(1024) void k_scan(const int* __restrict__ deg, int* __restrict__ ofs,
                                               float* __restrict__ rs) {
    __shared__ int wsum[16];
    const int m = blockIdx.x;
    const int* d = deg + (size_t)m * NN;
    int* o = ofs + (size_t)m * (NN + 1);
    float* r = rs + (size_t)m * NN;
    const int tid = threadIdx.x;
    const int c0 = tid * 49;          // 1024*49 = 50176 >= NN

    int s = 0;
#pragma unroll 7
    for (int i = 0; i < 49; i++) {
        int idx = c0 + i;
        if (idx < NN) s += d[idx];
    }
    // block exclusive scan of s
    const int lane = tid & 63, w = tid >> 6;
    int v = s;
    for (int off = 1; off < 64; off <<= 1) {
        int t = __shfl_up(v, off);
        if (lane >= off) v += t;
    }
    if (lane == 63) wsum[w] = v;
    __syncthreads();
    if (tid == 0) {
        int run = 0;
        for (int j = 0; j < 16; j++) { int t = wsum[j]; wsum[j] = run; run += t; }
    }
    __syncthreads();
    int run = wsum[w] + v - s;        // exclusive prefix for this thread's chunk
#pragma unroll 7
    for (int i = 0; i < 49; i++) {
        int idx = c0 + i;
        if (idx < NN) {
            int dv = d[idx];
            o[idx] = run;
            r[idx] = rsqrtf((float)(dv + 1));
            run += dv;
        }
    }
    if (tid == 1023) o[NN] = run;
}

// ---------------- CSR fill, XCD-partitioned by dst range ----------------
__global__ __launch_bounds__(256) void k_fill(const int* __restrict__ ei, int* __restrict__ deg,
                                              const int* __restrict__ ofs, int* __restrict__ sorted) {
    const int m = blockIdx.y;
    const int part = blockIdx.x & 7;
    const int slice = blockIdx.x >> 3;
    const int lo = part * PSZ, hi = lo + PSZ;
    const int4* s4 = (const int4*)(ei + (size_t)m * 2 * EE);
    const int4* d4 = (const int4*)(ei + (size_t)m * 2 * EE + EE);
    int* dg = deg + m * NN;
    const int* of = ofs + (size_t)m * (NN + 1);
    int* srt = sorted + (size_t)m * EE;
    const int base = slice * CHUNK4;
    for (int q = base + threadIdx.x; q < base + CHUNK4; q += 256) {
        int4 dv = d4[q];
        int4 sv = s4[q];
        if (dv.x >= lo && dv.x < hi) { int old = atomicSub(&dg[dv.x], 1); srt[of[dv.x] + old - 1] = sv.x; }
        if (dv.y >= lo && dv.y < hi) { int old = atomicSub(&dg[dv.y], 1); srt[of[dv.y] + old - 1] = sv.y; }
        if (dv.z >= lo && dv.z < hi) { int old = atomicSub(&dg[dv.z], 1); srt[of[dv.z] + old - 1] = sv.z; }
        if (dv.w >= lo && dv.w < hi) { int old = atomicSub(&dg[dv.w], 1); srt[of[dv.w] + old - 1] = sv.w; }
    }
}

// ---------------- shared GEMM tile core: in_tile [64][68], w [k][OD] ----------------
template <int OD>
__device__ __forceinline__ void gemm_tile_compute(const float* lds_in, const float* lds_w,
                                                  float (*acc)[4], int tid) {
    constexpr int CG = OD / 4;
    constexpr int NP = 256 / CG;
    constexpr int NPASS = 64 / NP;
    const int cg = tid % CG;
    const int nid = tid / CG;
    for (int k0 = 0; k0 < 64; k0 += 8) {
        float4 w[8];
#pragma unroll
        for (int j = 0; j < 8; j++) w[j] = *(const float4*)&lds_w[(k0 + j) * OD + cg * 4];
#pragma unroll
        for (int p = 0; p < NPASS; p++) {
            const float* xr = &lds_in[(nid + p * NP) * 68 + k0];
            float4 xa = *(const float4*)xr;
            float4 xb = *(const float4*)(xr + 4);
            float xs[8] = {xa.x, xa.y, xa.z, xa.w, xb.x, xb.y, xb.z, xb.w};
#pragma unroll
            for (int j = 0; j < 8; j++) {
                acc[p][0] = fmaf(xs[j], w[j].x, acc[p][0]);
                acc[p][1] = fmaf(xs[j], w[j].y, acc[p][1]);
                acc[p][2] = fmaf(xs[j], w[j].z, acc[p][2]);
                acc[p][3] = fmaf(xs[j], w[j].w, acc[p][3]);
            }
        }
    }
}

// ---------------- generic per-head GEMM: out = act(in @ W + b) ----------------
template <int KD, int OD, int ACT, bool HAS_B>
__global__ __launch_bounds__(256) void k_gemm(const float* __restrict__ in, long in_sh,
                                              const float* __restrict__ W,
                                              const float* __restrict__ B,
                                              float* __restrict__ out, long out_sh) {
    __shared__ float lds_in[64 * 68];
    __shared__ float lds_w[KD * OD];
    __shared__ float lds_b[OD];
    const int hd = blockIdx.y, tid = threadIdx.x;
    const int nbase = blockIdx.x * 64;
    const float* gin = in + (long)hd * in_sh;
    const float* gw = W + (long)hd * KD * OD;

    for (int qq = tid; qq < KD * OD / 4; qq += 256)
        ((float4*)lds_w)[qq] = ((const float4*)gw)[qq];
    if (tid < OD) lds_b[tid] = HAS_B ? B[(long)hd * OD + tid] : 0.f;

    constexpr int CG = OD / 4, NP = 256 / CG, NPASS = 64 / NP;
    float acc[NPASS][4];
#pragma unroll
    for (int p = 0; p < NPASS; p++) acc[p][0] = acc[p][1] = acc[p][2] = acc[p][3] = 0.f;

    for (int ks = 0; ks < KD; ks += 64) {
        __syncthreads();
        for (int qq = tid; qq < 64 * 16; qq += 256) {
            int node = qq >> 4, k4 = qq & 15;
            int ng = nbase + node;
            float4 v = make_float4(0.f, 0.f, 0.f, 0.f);
            if (ng < NN) v = *(const float4*)&gin[(long)ng * KD + ks + k4 * 4];
            *(float4*)&lds_in[node * 68 + k4 * 4] = v;
        }
        __syncthreads();
        gemm_tile_compute<OD>(lds_in, lds_w + ks * OD, acc, tid);
    }

    const int cg = tid % CG, nid = tid / CG;
    float* gout = out + (long)hd * out_sh;
#pragma unroll
    for (int p = 0; p < NPASS; p++) {
        int ng = nbase + nid + p * NP;
        if (ng < NN) {
            float4 r;
            r.x = acc[p][0] + lds_b[cg * 4 + 0];
            r.y = acc[p][1] + lds_b[cg * 4 + 1];
            r.z = acc[p][2] + lds_b[cg * 4 + 2];
            r.w = acc[p][3] + lds_b[cg * 4 + 3];
            if (ACT == 1) { r.x = lrelu(r.x); r.y = lrelu(r.y); r.z = lrelu(r.z); r.w = lrelu(r.w); }
            *(float4*)&gout[(long)ng * OD + cg * 4] = r;
        }
    }
}

// ---------------- CSR gather: one wave per dst ----------------
__global__ __launch_bounds__(256) void k_gather(const int* __restrict__ sorted,
                                                const int* __restrict__ ofs,
                                                const float* __restrict__ rs,
                                                const float* __restrict__ xw,
                                                float* __restrict__ gg) {
    const int tid = threadIdx.x;
    const int dst = blockIdx.x * 4 + (tid >> 6);
    if (dst >= NN) return;
    const int lane = tid & 63;
    const int p = lane >> 5;
    const int cg = lane & 31;
    const size_t rowbase = (size_t)(cg >> 4) * NN * 16;  // head plane, float4 units
    const int c4 = cg & 15;
    const float4* x4 = (const float4*)xw;
    int beg = ofs[dst], end = ofs[dst + 1];
    float4 acc = make_float4(0.f, 0.f, 0.f, 0.f);
    for (int j = beg + p; j < end; j += 2) {
        int src = sorted[j];
        float c = rs[src];
        float4 v = x4[rowbase + (size_t)src * 16 + c4];
        acc.x = fmaf(c, v.x, acc.x);
        acc.y = fmaf(c, v.y, acc.y);
        acc.z = fmaf(c, v.z, acc.z);
        acc.w = fmaf(c, v.w, acc.w);
    }
    acc.x += __shfl_down(acc.x, 32);
    acc.y += __shfl_down(acc.y, 32);
    acc.z += __shfl_down(acc.z, 32);
    acc.w += __shfl_down(acc.w, 32);
    if (p == 0) {
        float rsd = rs[dst];
        float4 r = make_float4(acc.x * rsd, acc.y * rsd, acc.z * rsd, acc.w * rsd);
        ((float4*)gg)[rowbase + (size_t)dst * 16 + c4] = r;
    }
}

// ---------------- post: lrelu(agg + xw/deg + b_conv) @ W_dec + b_dec -> z ----------------
__global__ __launch_bounds__(256) void k_post(const float* __restrict__ gg,
                                              const float* __restrict__ xw,
                                              const int* __restrict__ ofs,
                                              const float* __restrict__ bconv,
                                              const float* __restrict__ Wdec,
                                              const float* __restrict__ bdec,
                                              float* __restrict__ zout) {
    constexpr int KD = 64, OD = 32;
    __shared__ float lds_in[64 * 68];
    __shared__ float lds_w[KD * OD];
    __shared__ float lds_b[OD];
    const int hd = blockIdx.y, tid = threadIdx.x;
    const int nbase = blockIdx.x * 64;

    for (int qq = tid; qq < 64 * 16; qq += 256) {
        int node = qq >> 4, k4 = qq & 15;
        int ng = nbase + node;
        float4 v = make_float4(0.f, 0.f, 0.f, 0.f);
        if (ng < NN) {
            int cnt = ofs[ng + 1] - ofs[ng];
            float idg = 1.f / (float)(cnt + 1);
            float4 a = *(const float4*)&gg[((size_t)hd * NN + ng) * 64 + k4 * 4];
            float4 xv = *(const float4*)&xw[((size_t)hd * NN + ng) * 64 + k4 * 4];
            float4 bb = *(const float4*)&bconv[hd * 64 + k4 * 4];
            v.x = lrelu(fmaf(xv.x, idg, a.x) + bb.x);
            v.y = lrelu(fmaf(xv.y, idg, a.y) + bb.y);
            v.z = lrelu(fmaf(xv.z, idg, a.z) + bb.z);
            v.w = lrelu(fmaf(xv.w, idg, a.w) + bb.w);
        }
        *(float4*)&lds_in[node * 68 + k4 * 4] = v;
    }
    for (int qq = tid; qq < KD * OD / 4; qq += 256)
        ((float4*)lds_w)[qq] = ((const float4*)(Wdec + (size_t)hd * KD * OD))[qq];
    if (tid < OD) lds_b[tid] = bdec[hd * OD + tid];
    __syncthreads();

    constexpr int CG = OD / 4, NP = 256 / CG, NPASS = 64 / NP;
    float acc[NPASS][4];
#pragma unroll
    for (int p = 0; p < NPASS; p++) acc[p][0] = acc[p][1] = acc[p][2] = acc[p][3] = 0.f;
    gemm_tile_compute<OD>(lds_in, lds_w, acc, tid);

    const int cg = tid % CG, nid = tid / CG;
#pragma unroll
    for (int p = 0; p < NPASS; p++) {
        int ng = nbase + nid + p * NP;
        if (ng < NN) {
            float4 r;
            r.x = acc[p][0] + lds_b[cg * 4 + 0];
            r.y = acc[p][1] + lds_b[cg * 4 + 1];
            r.z = acc[p][2] + lds_b[cg * 4 + 2];
            r.w = acc[p][3] + lds_b[cg * 4 + 3];
            *(float4*)&zout[(size_t)ng * 64 + hd * 32 + cg * 4] = r;
        }
    }
}

// ---------------- semantic attention scores ----------------
__global__ __launch_bounds__(256) void k_score(const float* __restrict__ z,
                                               const float* __restrict__ Ws,
                                               const float* __restrict__ bs,
                                               const float* __restrict__ qv,
                                               float* __restrict__ score) {
    constexpr int KD = 64, OD = 128;
    __shared__ float lds_in[64 * 68];
    __shared__ float lds_w[KD * OD];
    __shared__ float lds_b[OD];
    const int m = blockIdx.y, tid = threadIdx.x;
    const int nbase = blockIdx.x * 64;
    const float* gin = z + (size_t)m * NN * 64;

    for (int qq = tid; qq < 64 * 16; qq += 256) {
        int node = qq >> 4, k4 = qq & 15;
        int ng = nbase + node;
        float4 v = make_float4(0.f, 0.f, 0.f, 0.f);
        if (ng < NN) v = *(const float4*)&gin[(size_t)ng * 64 + k4 * 4];
        *(float4*)&lds_in[node * 68 + k4 * 4] = v;
    }
    for (int qq = tid; qq < KD * OD / 4; qq += 256)
        ((float4*)lds_w)[qq] = ((const float4*)Ws)[qq];
    if (tid < OD) lds_b[tid] = bs[tid];
    __syncthreads();

    constexpr int CG = 32, NP = 8, NPASS = 8;
    float acc[NPASS][4];
#pragma unroll
    for (int p = 0; p < NPASS; p++) acc[p][0] = acc[p][1] = acc[p][2] = acc[p][3] = 0.f;
    gemm_tile_compute<OD>(lds_in, lds_w, acc, tid);

    const int cg = tid % CG, nid = tid / CG;
    float4 qf = *(const float4*)&qv[cg * 4];
    float s = 0.f;
#pragma unroll
    for (int p = 0; p < NPASS; p++) {
        int ng = nbase + nid + p * NP;
        if (ng < NN) {
            s += fast_tanh(acc[p][0] + lds_b[cg * 4 + 0]) * qf.x;
            s += fast_tanh(acc[p][1] + lds_b[cg * 4 + 1]) * qf.y;
            s += fast_tanh(acc[p][2] + lds_b[cg * 4 + 2]) * qf.z;
            s += fast_tanh(acc[p][3] + lds_b[cg * 4 + 3]) * qf.w;
        }
    }
    for (int off = 32; off > 0; off >>= 1) s += __shfl_down(s, off);
    if ((tid & 63) == 0) atomicAdd(&score[m], s);
}

// ---------------- beta = softmax(score/N) ----------------
__global__ void k_beta(const float* __restrict__ score, float* __restrict__ beta_ws,
                       float* __restrict__ out) {
    if (threadIdx.x == 0) {
        float s0 = score[0] / (float)NN, s1 = score[1] / (float)NN, s2 = score[2] / (float)NN;
        float mx = fmaxf(s0, fmaxf(s1, s2));
        float e0 = expf(s0 - mx), e1 = expf(s1 - mx), e2 = expf(s2 - mx);
        float inv = 1.f / (e0 + e1 + e2);
        beta_ws[0] = e0 * inv; beta_ws[1] = e1 * inv; beta_ws[2] = e2 * inv;
        out[800000] = e0 * inv; out[800001] = e1 * inv; out[800002] = e2 * inv;
    }
}

// ---------------- output: log_softmax((beta . z) @ W_o + b_o) ----------------
__global__ __launch_bounds__(256) void k_out(const float* __restrict__ z,
                                             const float* __restrict__ beta,
                                             const float* __restrict__ Wo,
                                             const float* __restrict__ bo,
                                             float* __restrict__ out) {
    __shared__ float Zt[64 * 68];
    __shared__ float Wl[64 * 16];
    __shared__ float bl[16];
    const int tid = threadIdx.x, nbase = blockIdx.x * 64;
    float b0 = beta[0], b1 = beta[1], b2 = beta[2];
    for (int qq = tid; qq < 64 * 16; qq += 256) {
        int node = qq >> 4, k4 = qq & 15;
        int ng = nbase + node;
        float4 v = make_float4(0.f, 0.f, 0.f, 0.f);
        if (ng < NN) {
            float4 z0 = *(const float4*)&z[((size_t)0 * NN + ng) * 64 + k4 * 4];
            float4 z1 = *(const float4*)&z[((size_t)1 * NN + ng) * 64 + k4 * 4];
            float4 z2 = *(const float4*)&z[((size_t)2 * NN + ng) * 64 + k4 * 4];
            v.x = b0 * z0.x + b1 * z1.x + b2 * z2.x;
            v.y = b0 * z0.y + b1 * z1.y + b2 * z2.y;
            v.z = b0 * z0.z + b1 * z1.z + b2 * z2.z;
            v.w = b0 * z0.w + b1 * z1.w + b2 * z2.w;
        }
        *(float4*)&Zt[node * 68 + k4 * 4] = v;
    }
    for (int qq = tid; qq < 64 * 16 / 4; qq += 256)
        ((float4*)Wl)[qq] = ((const float4*)Wo)[qq];
    if (tid < 16) bl[tid] = bo[tid];
    __syncthreads();

    const int node = tid >> 2, cg = tid & 3;
    float4 a = make_float4(bl[cg * 4 + 0], bl[cg * 4 + 1], bl[cg * 4 + 2], bl[cg * 4 + 3]);
    for (int k = 0; k < 64; k++) {
        float zv = Zt[node * 68 + k];
        float4 w = *(const float4*)&Wl[k * 16 + cg * 4];
        a.x = fmaf(zv, w.x, a.x);
        a.y = fmaf(zv, w.y, a.y);
        a.z = fmaf(zv, w.z, a.z);
        a.w = fmaf(zv, w.w, a.w);
    }
    float mx = fmaxf(fmaxf(a.x, a.y), fmaxf(a.z, a.w));
    mx = fmaxf(mx, __shfl_xor(mx, 1));
    mx = fmaxf(mx, __shfl_xor(mx, 2));
    float sm = expf(a.x - mx) + expf(a.y - mx) + expf(a.z - mx) + expf(a.w - mx);
    sm += __shfl_xor(sm, 1);
    sm += __shfl_xor(sm, 2);
    float lse = mx + logf(sm);
    int ng = nbase + node;
    if (ng < NN) {
        float4 r = make_float4(a.x - lse, a.y - lse, a.z - lse, a.w - lse);
        *(float4*)&out[(size_t)ng * 16 + cg * 4] = r;
    }
}

extern "C" void kernel_launch(void* const* d_in, const int* in_sizes, int n_in,
                              void* d_out, int out_size, void* d_ws, size_t ws_size,
                              hipStream_t stream) {
    const float* x      = (const float*)d_in[0];
    const int*   ei     = (const int*)d_in[1];
    const float* W_enc  = (const float*)d_in[2];
    const float* b_enc  = (const float*)d_in[3];
    const float* W_conv = (const float*)d_in[4];
    const float* b_conv = (const float*)d_in[5];
    const float* W_dec  = (const float*)d_in[6];
    const float* b_dec  = (const float*)d_in[7];
    const float* W_s    = (const float*)d_in[8];
    const float* b_s    = (const float*)d_in[9];
    const float* qv     = (const float*)d_in[10];
    const float* W_o    = (const float*)d_in[11];
    const float* b_o    = (const float*)d_in[12];
    float* out = (float*)d_out;

    char* ws = (char*)d_ws;
    size_t off = 0;
    auto alloc = [&](size_t bytes) -> char* {
        char* p = ws + off;
        off = (off + bytes + 255) & ~(size_t)255;
        return p;
    };
    int*   deg_i   = (int*)alloc((size_t)MM * NN * 4);
    int*   row_ofs = (int*)alloc((size_t)MM * (NN + 1) * 4);
    float* rs      = (float*)alloc((size_t)MM * NN * 4);
    int*   sorted  = (int*)alloc((size_t)MM * EE * 4);
    float* score   = (float*)alloc(64);
    float* beta_ws = (float*)alloc(64);
    float* h_buf   = (float*)alloc((size_t)HH * NN * 64 * 4);
    float* xw_buf  = (float*)alloc((size_t)HH * NN * 64 * 4);
    float* z_buf   = (float*)alloc((size_t)MM * NN * 64 * 4);
    float* gg_buf  = h_buf;  // h dead after conv; reuse as gather output

    hipMemsetAsync(deg_i, 0, (size_t)MM * NN * 4, stream);
    hipMemsetAsync(score, 0, 16, stream);

    dim3 gpart(NPART * NSLICE, MM);
    k_deg<<<gpart, 256, 0, stream>>>(ei, deg_i);
    k_scan<<<MM, 1024, 0, stream>>>(deg_i, row_ofs, rs);
    k_fill<<<gpart, 256, 0, stream>>>(ei, deg_i, row_ofs, sorted);

    dim3 gh((NN + 63) / 64, HH);
    for (int m = 0; m < MM; m++) {
        k_gemm<IND, HIDD, 1, true><<<gh, 256, 0, stream>>>(
            x, 0L, W_enc + (size_t)m * HH * IND * HIDD, b_enc + (size_t)m * HH * HIDD,
            h_buf, (long)NN * 64);
        k_gemm<HIDD, HIDD, 0, false><<<gh, 256, 0, stream>>>(
            h_buf, (long)NN * 64, W_conv + (size_t)m * HH * HIDD * HIDD, nullptr,
            xw_buf, (long)NN * 64);
        k_gather<<<(NN + 3) / 4, 256, 0, stream>>>(
            sorted + (size_t)m * EE, row_ofs + (size_t)m * (NN + 1), rs + (size_t)m * NN,
            xw_buf, gg_buf);
        k_post<<<gh, 256, 0, stream>>>(
            gg_buf, xw_buf, row_ofs + (size_t)m * (NN + 1), b_conv + (size_t)m * HH * HIDD,
            W_dec + (size_t)m * HH * HIDD * HEADD, b_dec + (size_t)m * HH * HEADD,
            z_buf + (size_t)m * NN * 64);
    }
    dim3 gs((NN + 63) / 64, MM);
    k_score<<<gs, 256, 0, stream>>>(z_buf, W_s, b_s, qv, score);
    k_beta<<<1, 64, 0, stream>>>(score, beta_ws, out);
    k_out<<<(NN + 63) / 64, 256, 0, stream>>>(z_buf, beta_ws, W_o, b_o, out);
}

// Round 3
// 822.008 us; speedup vs baseline: 1.4620x; 1.4564x over previous
//
#include <hip/hip_runtime.h>

#define NN 50000
#define EE 800000
#define MM 3
#define HH 2
#define IND 128
#define HIDD 64
#define HEADD 32
#define OUTD 16
#define ATTD 128

#define NPART 8
#define PSZ 6250
#define NSLICE 40
#define CHUNK4 5000

typedef unsigned short u16;
typedef short bf16x8 __attribute__((ext_vector_type(8)));
typedef float f32x4 __attribute__((ext_vector_type(4)));

__device__ __forceinline__ float lrelu(float v) { return v > 0.f ? v : 0.1f * v; }

__device__ __forceinline__ float fast_tanh(float x) {
    float ax = fabsf(x);
    float e = __expf(-2.0f * ax);
    float t = (1.0f - e) * __builtin_amdgcn_rcpf(1.0f + e);
    return copysignf(t, x);
}

__device__ __forceinline__ u16 f2b(float f) {          // fp32 -> bf16 RNE
    union { float f; unsigned int u; } v; v.f = f;
    unsigned int r = v.u + 0x7fffu + ((v.u >> 16) & 1u);
    return (u16)(r >> 16);
}
__device__ __forceinline__ float b2f(u16 u) {
    union { unsigned int u; float f; } v; v.u = ((unsigned int)u) << 16; return v.f;
}

// ================= graph preprocessing (unchanged from R2) =================
__global__ __launch_bounds__(256) void k_deg(const int* __restrict__ ei, int* __restrict__ deg) {
    const int m = blockIdx.y;
    const int part = blockIdx.x & 7;
    const int slice = blockIdx.x >> 3;
    const int lo = part * PSZ, hi = lo + PSZ;
    const int4* d4 = (const int4*)(ei + (size_t)m * 2 * EE + EE);
    int* dg = deg + m * NN;
    const int base = slice * CHUNK4;
    for (int q = base + threadIdx.x; q < base + CHUNK4; q += 256) {
        int4 v = d4[q];
        if (v.x >= lo && v.x < hi) atomicAdd(&dg[v.x], 1);
        if (v.y >= lo && v.y < hi) atomicAdd(&dg[v.y], 1);
        if (v.z >= lo && v.z < hi) atomicAdd(&dg[v.z], 1);
        if (v.w >= lo && v.w < hi) atomicAdd(&dg[v.w], 1);
    }
}

__global__ __launch_bounds__(1024) void k_scan(const int* __restrict__ deg, int* __restrict__ ofs,
                                               float* __restrict__ rs) {
    __shared__ int wsum[16];
    const int m = blockIdx.x;
    const int* d = deg + (size_t)m * NN;
    int* o = ofs + (size_t)m * (NN + 1);
    float* r = rs + (size_t)m * NN;
    const int tid = threadIdx.x;
    const int c0 = tid * 49;
    int s = 0;
#pragma unroll 7
    for (int i = 0; i < 49; i++) { int idx = c0 + i; if (idx < NN) s += d[idx]; }
    const int lane = tid & 63, w = tid >> 6;
    int v = s;
    for (int off = 1; off < 64; off <<= 1) { int t = __shfl_up(v, off); if (lane >= off) v += t; }
    if (lane == 63) wsum[w] = v;
    __syncthreads();
    if (tid == 0) { int run = 0; for (int j = 0; j < 16; j++) { int t = wsum[j]; wsum[j] = run; run += t; } }
    __syncthreads();
    int run = wsum[w] + v - s;
#pragma unroll 7
    for (int i = 0; i < 49; i++) {
        int idx = c0 + i;
        if (idx < NN) {
            int dv = d[idx];
            o[idx] = run;
            r[idx] = rsqrtf((float)(dv + 1));
            run += dv;
        }
    }
    if (tid == 1023) o[NN] = run;
}

__global__ __launch_bounds__(256) void k_fill(const int* __restrict__ ei, int* __restrict__ deg,
                                              const int* __restrict__ ofs, int* __restrict__ sorted) {
    const int m = blockIdx.y;
    const int part = blockIdx.x & 7;
    const int slice = blockIdx.x >> 3;
    const int lo = part * PSZ, hi = lo + PSZ;
    const int4* s4 = (const int4*)(ei + (size_t)m * 2 * EE);
    const int4* d4 = (const int4*)(ei + (size_t)m * 2 * EE + EE);
    int* dg = deg + m * NN;
    const int* of = ofs + (size_t)m * (NN + 1);
    int* srt = sorted + (size_t)m * EE;
    const int base = slice * CHUNK4;
    for (int q = base + threadIdx.x; q < base + CHUNK4; q += 256) {
        int4 dv = d4[q];
        int4 sv = s4[q];
        if (dv.x >= lo && dv.x < hi) { int old = atomicSub(&dg[dv.x], 1); srt[of[dv.x] + old - 1] = sv.x; }
        if (dv.y >= lo && dv.y < hi) { int old = atomicSub(&dg[dv.y], 1); srt[of[dv.y] + old - 1] = sv.y; }
        if (dv.z >= lo && dv.z < hi) { int old = atomicSub(&dg[dv.z], 1); srt[of[dv.z] + old - 1] = sv.z; }
        if (dv.w >= lo && dv.w < hi) { int old = atomicSub(&dg[dv.w], 1); srt[of[dv.w] + old - 1] = sv.w; }
    }
}

// ================= weight prep: fp32 -> bf16 MFMA B-fragment layout =================
// slot = 64 lanes * 8 values; B-frag: value[j] = W[k = ks*32 + (lane>>4)*8 + j][n = nt*16 + (lane&15)]
__global__ __launch_bounds__(256) void k_prep(const float* __restrict__ We, const float* __restrict__ Wc,
                                              const float* __restrict__ Wd, const float* __restrict__ Ws,
                                              u16* __restrict__ wbe, u16* __restrict__ wbc,
                                              u16* __restrict__ wbd, u16* __restrict__ wbs) {
    int t = blockIdx.x * 256 + threadIdx.x;
    if (t >= 11776) return;
    bf16x8 val;
    u16* dst;
    if (t < 6144) {                       // enc: per m, 8 nt x 4 ks x 64 lanes, K=128, N=128
        int m = t >> 11, r = t & 2047;
        int nt = r >> 8, ks = (r >> 6) & 3, lane = r & 63;
        int n = nt * 16 + (lane & 15), h = n >> 6, o = n & 63;
        int kb = ks * 32 + (lane >> 4) * 8;
        const float* w = We + ((size_t)(m * 2 + h) * 128) * 64;
#pragma unroll
        for (int j = 0; j < 8; j++) val[j] = (short)f2b(w[(size_t)(kb + j) * 64 + o]);
        dst = wbe + ((size_t)m * 2048 + r) * 8;
    } else if (t < 9216) {                // conv: per m, 8 nt x 2 ks, K=64, N=128 (head-blockdiag)
        int u = t - 6144;
        int m = u >> 10, r = u & 1023;
        int nt = r >> 7, ks = (r >> 6) & 1, lane = r & 63;
        int h = nt >> 2, o = (nt & 3) * 16 + (lane & 15);
        int kb = ks * 32 + (lane >> 4) * 8;
        const float* w = Wc + ((size_t)(m * 2 + h) * 64) * 64;
#pragma unroll
        for (int j = 0; j < 8; j++) val[j] = (short)f2b(w[(size_t)(kb + j) * 64 + o]);
        dst = wbc + ((size_t)m * 1024 + r) * 8;
    } else if (t < 10752) {               // dec: per m, 4 nt x 2 ks, K=64, N=64 (head-blockdiag)
        int u = t - 9216;
        int m = u >> 9, r = u & 511;
        int nt = r >> 7, ks = (r >> 6) & 1, lane = r & 63;
        int h = nt >> 1, o = (nt & 1) * 16 + (lane & 15);
        int kb = ks * 32 + (lane >> 4) * 8;
        const float* w = Wd + ((size_t)(m * 2 + h) * 64) * 32;
#pragma unroll
        for (int j = 0; j < 8; j++) val[j] = (short)f2b(w[(size_t)(kb + j) * 32 + o]);
        dst = wbd + ((size_t)m * 512 + r) * 8;
    } else {                              // W_s: 8 nt x 2 ks, K=64, N=128
        int r = t - 10752;
        int nt = r >> 7, ks = (r >> 6) & 1, lane = r & 63;
        int n = nt * 16 + (lane & 15);
        int kb = ks * 32 + (lane >> 4) * 8;
#pragma unroll
        for (int j = 0; j < 8; j++) val[j] = (short)f2b(Ws[(size_t)(kb + j) * 128 + n]);
        dst = wbs + (size_t)r * 8;
    }
    *(bf16x8*)dst = val;
}

// ================= enc: h = lrelu(x @ W_enc + b_enc), bf16 MFMA, no LDS =================
__global__ __launch_bounds__(256) void k_enc(const float* __restrict__ x,
                                             const u16* __restrict__ wbe,
                                             const float* __restrict__ be,
                                             u16* __restrict__ h) {
    const int tid = threadIdx.x, lane = tid & 63, wave = tid >> 6;
    const int quad = lane >> 4, c16 = lane & 15;
    const int row = blockIdx.x * 64 + wave * 16 + c16;
    const bool ok = row < NN;
    const bf16x8* wb = (const bf16x8*)wbe;
    f32x4 acc[8];
    f32x4 zero = {0.f, 0.f, 0.f, 0.f};
#pragma unroll
    for (int nt = 0; nt < 8; nt++) acc[nt] = zero;
#pragma unroll
    for (int ks = 0; ks < 4; ks++) {
        bf16x8 a = {0, 0, 0, 0, 0, 0, 0, 0};
        if (ok) {
            const float* xp = x + (size_t)row * 128 + ks * 32 + quad * 8;
            float4 xa = *(const float4*)xp;
            float4 xb = *(const float4*)(xp + 4);
            a[0] = (short)f2b(xa.x); a[1] = (short)f2b(xa.y);
            a[2] = (short)f2b(xa.z); a[3] = (short)f2b(xa.w);
            a[4] = (short)f2b(xb.x); a[5] = (short)f2b(xb.y);
            a[6] = (short)f2b(xb.z); a[7] = (short)f2b(xb.w);
        }
#pragma unroll
        for (int nt = 0; nt < 8; nt++)
            acc[nt] = __builtin_amdgcn_mfma_f32_16x16x32_bf16(a, wb[(nt * 4 + ks) * 64 + lane], acc[nt], 0, 0, 0);
    }
    const int rb = blockIdx.x * 64 + wave * 16 + quad * 4;
#pragma unroll
    for (int nt = 0; nt < 8; nt++) {
        int col = nt * 16 + c16, hh = col >> 6, o = col & 63;
        float bias = be[hh * 64 + o];
#pragma unroll
        for (int j = 0; j < 4; j++) {
            int r = rb + j;
            if (r < NN) h[(size_t)r * 128 + col] = f2b(lrelu(acc[nt][j] + bias));
        }
    }
}

// ================= conv: xw = h @ W_conv (per-head block-diag) =================
__global__ __launch_bounds__(256) void k_conv(const u16* __restrict__ h,
                                              const u16* __restrict__ wbc,
                                              u16* __restrict__ xw) {
    const int tid = threadIdx.x, lane = tid & 63, wave = tid >> 6;
    const int quad = lane >> 4, c16 = lane & 15;
    const int row = blockIdx.x * 64 + wave * 16 + c16;
    const bool ok = row < NN;
    const bf16x8* wb = (const bf16x8*)wbc;
    f32x4 acc[8];
    f32x4 zero = {0.f, 0.f, 0.f, 0.f};
#pragma unroll
    for (int nt = 0; nt < 8; nt++) acc[nt] = zero;
#pragma unroll
    for (int ks = 0; ks < 2; ks++) {
        bf16x8 a0 = {0,0,0,0,0,0,0,0}, a1 = {0,0,0,0,0,0,0,0};
        if (ok) {
            int k0 = ks * 32 + quad * 8;
            a0 = *(const bf16x8*)&h[(size_t)row * 128 + k0];
            a1 = *(const bf16x8*)&h[(size_t)row * 128 + 64 + k0];
        }
#pragma unroll
        for (int nt = 0; nt < 8; nt++)
            acc[nt] = __builtin_amdgcn_mfma_f32_16x16x32_bf16(nt < 4 ? a0 : a1, wb[(nt * 2 + ks) * 64 + lane], acc[nt], 0, 0, 0);
    }
    const int rb = blockIdx.x * 64 + wave * 16 + quad * 4;
#pragma unroll
    for (int nt = 0; nt < 8; nt++) {
        int col = nt * 16 + c16;
#pragma unroll
        for (int j = 0; j < 4; j++) {
            int r = rb + j;
            if (r < NN) xw[(size_t)r * 128 + col] = f2b(acc[nt][j]);
        }
    }
}

// ================= gather: gg[dst] = rs[dst] * sum_src rs[src]*xw[src] =================
__global__ __launch_bounds__(256) void k_gather(const int* __restrict__ sorted,
                                                const int* __restrict__ ofs,
                                                const float* __restrict__ rs,
                                                const u16* __restrict__ xw,
                                                u16* __restrict__ gg) {
    const int tid = threadIdx.x;
    const int dst = blockIdx.x * 4 + (tid >> 6);
    if (dst >= NN) return;
    const int lane = tid & 63, p = lane >> 5, c = lane & 31;
    int beg = ofs[dst], end = ofs[dst + 1];
    float a0 = 0.f, a1 = 0.f, a2 = 0.f, a3 = 0.f;
    for (int j = beg + p; j < end; j += 2) {
        int s = sorted[j];
        float cf = rs[s];
        ushort4 v = *(const ushort4*)&xw[(size_t)s * 128 + c * 4];
        a0 = fmaf(cf, b2f(v.x), a0);
        a1 = fmaf(cf, b2f(v.y), a1);
        a2 = fmaf(cf, b2f(v.z), a2);
        a3 = fmaf(cf, b2f(v.w), a3);
    }
    a0 += __shfl_down(a0, 32);
    a1 += __shfl_down(a1, 32);
    a2 += __shfl_down(a2, 32);
    a3 += __shfl_down(a3, 32);
    if (p == 0) {
        float rsd = rs[dst];
        ushort4 o;
        o.x = f2b(a0 * rsd); o.y = f2b(a1 * rsd);
        o.z = f2b(a2 * rsd); o.w = f2b(a3 * rsd);
        *(ushort4*)&gg[(size_t)dst * 128 + c * 4] = o;
    }
}

// ================= post+score: z = lrelu(gg + xw/deg + b_conv) @ W_dec + b_dec; score += sum tanh(z@Ws+bs).q
__global__ __launch_bounds__(256) void k_post(const u16* __restrict__ gg,
                                              const u16* __restrict__ xw,
                                              const float* __restrict__ rs,
                                              const float* __restrict__ bconv,
                                              const u16* __restrict__ wbd,
                                              const float* __restrict__ bdec,
                                              const u16* __restrict__ wbs,
                                              const float* __restrict__ bs,
                                              const float* __restrict__ qv,
                                              float* __restrict__ z,
                                              float* __restrict__ score, int m) {
    __shared__ float zl[64 * 68];
    const int tid = threadIdx.x, lane = tid & 63, wave = tid >> 6;
    const int quad = lane >> 4, c16 = lane & 15;
    const int row = blockIdx.x * 64 + wave * 16 + c16;
    const bool ok = row < NN;
    float rs2 = 0.f;
    if (ok) { float t = rs[row]; rs2 = t * t; }
    const bf16x8* wd = (const bf16x8*)wbd;
    f32x4 acc[4];
    f32x4 zero = {0.f, 0.f, 0.f, 0.f};
#pragma unroll
    for (int nt = 0; nt < 4; nt++) acc[nt] = zero;
#pragma unroll
    for (int ks = 0; ks < 2; ks++) {
        bf16x8 a0 = {0,0,0,0,0,0,0,0}, a1 = {0,0,0,0,0,0,0,0};
        if (ok) {
            int k0 = ks * 32 + quad * 8;
            const u16* gp0 = &gg[(size_t)row * 128 + k0];
            const u16* xp0 = &xw[(size_t)row * 128 + k0];
            const u16* gp1 = gp0 + 64;
            const u16* xp1 = xp0 + 64;
#pragma unroll
            for (int j = 0; j < 8; j++) {
                float v0 = lrelu(fmaf(b2f(xp0[j]), rs2, b2f(gp0[j])) + bconv[k0 + j]);
                float v1 = lrelu(fmaf(b2f(xp1[j]), rs2, b2f(gp1[j])) + bconv[64 + k0 + j]);
                a0[j] = (short)f2b(v0);
                a1[j] = (short)f2b(v1);
            }
        }
#pragma unroll
        for (int nt = 0; nt < 4; nt++)
            acc[nt] = __builtin_amdgcn_mfma_f32_16x16x32_bf16(nt < 2 ? a0 : a1, wd[(nt * 2 + ks) * 64 + lane], acc[nt], 0, 0, 0);
    }
    // z epilogue -> LDS (+0 padding for OOB rows), then coalesced global store
    const int rbl = wave * 16 + quad * 4;
#pragma unroll
    for (int nt = 0; nt < 4; nt++) {
        int col = nt * 16 + c16, hh = col >> 5, o = col & 31;
        float bias = bdec[hh * 32 + o];
#pragma unroll
        for (int j = 0; j < 4; j++) {
            int rl = rbl + j;
            int rg = blockIdx.x * 64 + rl;
            zl[rl * 68 + col] = (rg < NN) ? (acc[nt][j] + bias) : 0.f;
        }
    }
    __syncthreads();
    {
        int rl = tid >> 2, cq = tid & 3;
        int rg = blockIdx.x * 64 + rl;
        if (rg < NN) {
#pragma unroll
            for (int i = 0; i < 4; i++) {
                int c4 = (cq * 4 + i) * 4;
                *(float4*)&z[(size_t)rg * 64 + c4] = *(const float4*)&zl[rl * 68 + c4];
            }
        }
    }
    // score GEMM: A = z tile (from LDS), B = W_s frags
    const bf16x8* wsb = (const bf16x8*)wbs;
    f32x4 sa[8];
#pragma unroll
    for (int nt = 0; nt < 8; nt++) sa[nt] = zero;
#pragma unroll
    for (int ks = 0; ks < 2; ks++) {
        bf16x8 a;
        const float* zp = &zl[(wave * 16 + c16) * 68 + ks * 32 + quad * 8];
#pragma unroll
        for (int j = 0; j < 8; j++) a[j] = (short)f2b(zp[j]);
#pragma unroll
        for (int nt = 0; nt < 8; nt++)
            sa[nt] = __builtin_amdgcn_mfma_f32_16x16x32_bf16(a, wsb[(nt * 2 + ks) * 64 + lane], sa[nt], 0, 0, 0);
    }
    float s = 0.f;
#pragma unroll
    for (int nt = 0; nt < 8; nt++) {
        int col = nt * 16 + c16;
        float qc = qv[col], bb = bs[col];
#pragma unroll
        for (int j = 0; j < 4; j++) {
            int rg = blockIdx.x * 64 + rbl + j;
            if (rg < NN) s += fast_tanh(sa[nt][j] + bb) * qc;
        }
    }
#pragma unroll
    for (int off = 1; off < 64; off <<= 1) s += __shfl_xor(s, off);
    if (lane == 0) atomicAdd(&score[m], s);
}

// ================= beta =================
__global__ void k_beta(const float* __restrict__ score, float* __restrict__ beta_ws,
                       float* __restrict__ out) {
    if (threadIdx.x == 0) {
        float s0 = score[0] / (float)NN, s1 = score[1] / (float)NN, s2 = score[2] / (float)NN;
        float mx = fmaxf(s0, fmaxf(s1, s2));
        float e0 = expf(s0 - mx), e1 = expf(s1 - mx), e2 = expf(s2 - mx);
        float inv = 1.f / (e0 + e1 + e2);
        beta_ws[0] = e0 * inv; beta_ws[1] = e1 * inv; beta_ws[2] = e2 * inv;
        out[800000] = e0 * inv; out[800001] = e1 * inv; out[800002] = e2 * inv;
    }
}

// ================= output: log_softmax((beta . z) @ W_o + b_o) =================
__global__ __launch_bounds__(256) void k_out(const float* __restrict__ z,
                                             const float* __restrict__ beta,
                                             const float* __restrict__ Wo,
                                             const float* __restrict__ bo,
                                             float* __restrict__ out) {
    __shared__ float Zt[64 * 68];
    __shared__ float Wl[64 * 16];
    __shared__ float bl[16];
    const int tid = threadIdx.x, nbase = blockIdx.x * 64;
    float b0 = beta[0], b1 = beta[1], b2 = beta[2];
    for (int qq = tid; qq < 64 * 16; qq += 256) {
        int node = qq >> 4, k4 = qq & 15;
        int ng = nbase + node;
        float4 v = make_float4(0.f, 0.f, 0.f, 0.f);
        if (ng < NN) {
            float4 z0 = *(const float4*)&z[((size_t)0 * NN + ng) * 64 + k4 * 4];
            float4 z1 = *(const float4*)&z[((size_t)1 * NN + ng) * 64 + k4 * 4];
            float4 z2 = *(const float4*)&z[((size_t)2 * NN + ng) * 64 + k4 * 4];
            v.x = b0 * z0.x + b1 * z1.x + b2 * z2.x;
            v.y = b0 * z0.y + b1 * z1.y + b2 * z2.y;
            v.z = b0 * z0.z + b1 * z1.z + b2 * z2.z;
            v.w = b0 * z0.w + b1 * z1.w + b2 * z2.w;
        }
        *(float4*)&Zt[node * 68 + k4 * 4] = v;
    }
    for (int qq = tid; qq < 64 * 16 / 4; qq += 256)
        ((float4*)Wl)[qq] = ((const float4*)Wo)[qq];
    if (tid < 16) bl[tid] = bo[tid];
    __syncthreads();

    const int node = tid >> 2, cg = tid & 3;
    float4 a = make_float4(bl[cg * 4 + 0], bl[cg * 4 + 1], bl[cg * 4 + 2], bl[cg * 4 + 3]);
    for (int k = 0; k < 64; k++) {
        float zv = Zt[node * 68 + k];
        float4 w = *(const float4*)&Wl[k * 16 + cg * 4];
        a.x = fmaf(zv, w.x, a.x);
        a.y = fmaf(zv, w.y, a.y);
        a.z = fmaf(zv, w.z, a.z);
        a.w = fmaf(zv, w.w, a.w);
    }
    float mx = fmaxf(fmaxf(a.x, a.y), fmaxf(a.z, a.w));
    mx = fmaxf(mx, __shfl_xor(mx, 1));
    mx = fmaxf(mx, __shfl_xor(mx, 2));
    float sm = expf(a.x - mx) + expf(a.y - mx) + expf(a.z - mx) + expf(a.w - mx);
    sm += __shfl_xor(sm, 1);
    sm += __shfl_xor(sm, 2);
    float lse = mx + logf(sm);
    int ng = nbase + node;
    if (ng < NN) {
        float4 r = make_float4(a.x - lse, a.y - lse, a.z - lse, a.w - lse);
        *(float4*)&out[(size_t)ng * 16 + cg * 4] = r;
    }
}

extern "C" void kernel_launch(void* const* d_in, const int* in_sizes, int n_in,
                              void* d_out, int out_size, void* d_ws, size_t ws_size,
                              hipStream_t stream) {
    const float* x      = (const float*)d_in[0];
    const int*   ei     = (const int*)d_in[1];
    const float* W_enc  = (const float*)d_in[2];
    const float* b_enc  = (const float*)d_in[3];
    const float* W_conv = (const float*)d_in[4];
    const float* b_conv = (const float*)d_in[5];
    const float* W_dec  = (const float*)d_in[6];
    const float* b_dec  = (const float*)d_in[7];
    const float* W_s    = (const float*)d_in[8];
    const float* b_s    = (const float*)d_in[9];
    const float* qv     = (const float*)d_in[10];
    const float* W_o    = (const float*)d_in[11];
    const float* b_o    = (const float*)d_in[12];
    float* out = (float*)d_out;

    char* ws = (char*)d_ws;
    size_t off = 0;
    auto alloc = [&](size_t bytes) -> char* {
        char* p = ws + off;
        off = (off + bytes + 255) & ~(size_t)255;
        return p;
    };
    int*   deg_i   = (int*)alloc((size_t)MM * NN * 4);
    int*   row_ofs = (int*)alloc((size_t)MM * (NN + 1) * 4);
    float* rs      = (float*)alloc((size_t)MM * NN * 4);
    int*   sorted  = (int*)alloc((size_t)MM * EE * 4);
    float* score   = (float*)alloc(64);
    float* beta_ws = (float*)alloc(64);
    u16*   wbe     = (u16*)alloc((size_t)MM * 2048 * 8 * 2);
    u16*   wbc     = (u16*)alloc((size_t)MM * 1024 * 8 * 2);
    u16*   wbd     = (u16*)alloc((size_t)MM * 512 * 8 * 2);
    u16*   wbs     = (u16*)alloc((size_t)1024 * 8 * 2);
    u16*   h_buf   = (u16*)alloc((size_t)NN * 128 * 2);      // per-m, reused
    u16*   xw_buf  = (u16*)alloc((size_t)NN * 128 * 2);      // per-m, reused
    u16*   gg_buf  = (u16*)alloc((size_t)NN * 128 * 2);      // per-m, reused
    float* z_buf   = (float*)alloc((size_t)MM * NN * 64 * 4); // all m (k_out)

    hipMemsetAsync(deg_i, 0, (size_t)MM * NN * 4, stream);
    hipMemsetAsync(score, 0, 16, stream);

    dim3 gpart(NPART * NSLICE, MM);
    k_deg<<<gpart, 256, 0, stream>>>(ei, deg_i);
    k_scan<<<MM, 1024, 0, stream>>>(deg_i, row_ofs, rs);
    k_fill<<<gpart, 256, 0, stream>>>(ei, deg_i, row_ofs, sorted);
    k_prep<<<46, 256, 0, stream>>>(W_enc, W_conv, W_dec, W_s, wbe, wbc, wbd, wbs);

    const int GB = (NN + 63) / 64;   // 782
    for (int m = 0; m < MM; m++) {
        k_enc<<<GB, 256, 0, stream>>>(x, wbe + (size_t)m * 2048 * 8,
                                      b_enc + (size_t)m * 2 * 64, h_buf);
        k_conv<<<GB, 256, 0, stream>>>(h_buf, wbc + (size_t)m * 1024 * 8, xw_buf);
        k_gather<<<(NN + 3) / 4, 256, 0, stream>>>(sorted + (size_t)m * EE,
                                                   row_ofs + (size_t)m * (NN + 1),
                                                   rs + (size_t)m * NN, xw_buf, gg_buf);
        k_post<<<GB, 256, 0, stream>>>(gg_buf, xw_buf, rs + (size_t)m * NN,
                                       b_conv + (size_t)m * 2 * 64,
                                       wbd + (size_t)m * 512 * 8,
                                       b_dec + (size_t)m * 2 * 32,
                                       wbs, b_s, qv,
                                       z_buf + (size_t)m * NN * 64, score, m);
    }
    k_beta<<<1, 64, 0, stream>>>(score, beta_ws, out);
    k_out<<<GB, 256, 0, stream>>>(z_buf, beta_ws, W_o, b_o, out);
}

// Round 4
// 679.144 us; speedup vs baseline: 1.7696x; 1.2104x over previous
//
#include <hip/hip_runtime.h>

#define NN 50000
#define EE 800000
#define MM 3
#define HH 2
#define IND 128
#define HIDD 64
#define HEADD 32
#define OUTD 16
#define ATTD 128

#define NPART 8
#define PSZ 6250
#define NSLICE 40
#define CHUNK4 5000

#define NB4 12500          // NN/4 int4 groups per metapath
#define SB 49              // scan blocks per metapath (49*256 int4 >= 12500)

typedef unsigned short u16;
typedef short bf16x8 __attribute__((ext_vector_type(8)));
typedef float f32x4 __attribute__((ext_vector_type(4)));

__device__ __forceinline__ float lrelu(float v) { return v > 0.f ? v : 0.1f * v; }

__device__ __forceinline__ float fast_tanh(float x) {
    float ax = fabsf(x);
    float e = __expf(-2.0f * ax);
    float t = (1.0f - e) * __builtin_amdgcn_rcpf(1.0f + e);
    return copysignf(t, x);
}

__device__ __forceinline__ u16 f2b(float f) {          // fp32 -> bf16 RNE
    union { float f; unsigned int u; } v; v.f = f;
    unsigned int r = v.u + 0x7fffu + ((v.u >> 16) & 1u);
    return (u16)(r >> 16);
}
__device__ __forceinline__ float b2f(u16 u) {
    union { unsigned int u; float f; } v; v.u = ((unsigned int)u) << 16; return v.f;
}

// ================= graph preprocessing =================
__global__ __launch_bounds__(256) void k_deg(const int* __restrict__ ei, int* __restrict__ deg) {
    const int m = blockIdx.y;
    const int part = blockIdx.x & 7;
    const int slice = blockIdx.x >> 3;
    const int lo = part * PSZ, hi = lo + PSZ;
    const int4* d4 = (const int4*)(ei + (size_t)m * 2 * EE + EE);
    int* dg = deg + m * NN;
    const int base = slice * CHUNK4;
    for (int q = base + threadIdx.x; q < base + CHUNK4; q += 256) {
        int4 v = d4[q];
        if (v.x >= lo && v.x < hi) atomicAdd(&dg[v.x], 1);
        if (v.y >= lo && v.y < hi) atomicAdd(&dg[v.y], 1);
        if (v.z >= lo && v.z < hi) atomicAdd(&dg[v.z], 1);
        if (v.w >= lo && v.w < hi) atomicAdd(&dg[v.w], 1);
    }
}

// ---- scan phase 1: per-block sums of 1024 degrees ----
__global__ __launch_bounds__(256) void k_scan1(const int* __restrict__ deg, int* __restrict__ bsum) {
    __shared__ int wsum[4];
    const int m = blockIdx.y, b = blockIdx.x, tid = threadIdx.x;
    const int4* d4 = (const int4*)(deg + (size_t)m * NN);
    int idx4 = b * 256 + tid;
    int s = 0;
    if (idx4 < NB4) { int4 v = d4[idx4]; s = v.x + v.y + v.z + v.w; }
    const int lane = tid & 63, w = tid >> 6;
    int v = s;
    for (int off = 1; off < 64; off <<= 1) { int t = __shfl_up(v, off); if (lane >= off) v += t; }
    if (lane == 63) wsum[w] = v;
    __syncthreads();
    if (tid == 0) bsum[m * SB + b] = wsum[0] + wsum[1] + wsum[2] + wsum[3];
}

// ---- scan phase 2: exclusive scan of the 3x49 block sums (in place) ----
__global__ __launch_bounds__(256) void k_scan2(int* __restrict__ bsum) {
    __shared__ int ld[MM * SB];
    const int tid = threadIdx.x;
    if (tid < MM * SB) ld[tid] = bsum[tid];
    __syncthreads();
    if (tid < MM) {
        int run = 0;
        for (int b = 0; b < SB; b++) { int t = ld[tid * SB + b]; ld[tid * SB + b] = run; run += t; }
    }
    __syncthreads();
    if (tid < MM * SB) bsum[tid] = ld[tid];
}

// ---- scan phase 3: intra-block scan + write ofs (exclusive) + rs ----
__global__ __launch_bounds__(256) void k_scan3(const int* __restrict__ deg, const int* __restrict__ bsum,
                                               int* __restrict__ ofs, float* __restrict__ rs) {
    __shared__ int wsum[4];
    const int m = blockIdx.y, b = blockIdx.x, tid = threadIdx.x;
    const int4* d4 = (const int4*)(deg + (size_t)m * NN);
    int* o = ofs + (size_t)m * (NN + 1);
    float* r = rs + (size_t)m * NN;
    int idx4 = b * 256 + tid;
    int4 dv = make_int4(0, 0, 0, 0);
    if (idx4 < NB4) dv = d4[idx4];
    int s = dv.x + dv.y + dv.z + dv.w;
    const int lane = tid & 63, w = tid >> 6;
    int v = s;
    for (int off = 1; off < 64; off <<= 1) { int t = __shfl_up(v, off); if (lane >= off) v += t; }
    if (lane == 63) wsum[w] = v;
    __syncthreads();
    int wexcl = 0;
    for (int j = 0; j < 4; j++) if (j < w) wexcl += wsum[j];
    int base = bsum[m * SB + b] + wexcl + (v - s);
    if (idx4 < NB4) {
        int e0 = base, e1 = e0 + dv.x, e2 = e1 + dv.y, e3 = e2 + dv.z;
        ((int4*)o)[idx4] = make_int4(e0, e1, e2, e3);
        float4 rv;
        rv.x = rsqrtf((float)(dv.x + 1));
        rv.y = rsqrtf((float)(dv.y + 1));
        rv.z = rsqrtf((float)(dv.z + 1));
        rv.w = rsqrtf((float)(dv.w + 1));
        ((float4*)r)[idx4] = rv;
    }
    if (b == SB - 1 && tid == 0) o[NN] = EE;
}

__global__ __launch_bounds__(256) void k_fill(const int* __restrict__ ei, int* __restrict__ deg,
                                              const int* __restrict__ ofs, int* __restrict__ sorted) {
    const int m = blockIdx.y;
    const int part = blockIdx.x & 7;
    const int slice = blockIdx.x >> 3;
    const int lo = part * PSZ, hi = lo + PSZ;
    const int4* s4 = (const int4*)(ei + (size_t)m * 2 * EE);
    const int4* d4 = (const int4*)(ei + (size_t)m * 2 * EE + EE);
    int* dg = deg + m * NN;
    const int* of = ofs + (size_t)m * (NN + 1);
    int* srt = sorted + (size_t)m * EE;
    const int base = slice * CHUNK4;
    for (int q = base + threadIdx.x; q < base + CHUNK4; q += 256) {
        int4 dv = d4[q];
        int4 sv = s4[q];
        if (dv.x >= lo && dv.x < hi) { int old = atomicSub(&dg[dv.x], 1); srt[of[dv.x] + old - 1] = sv.x; }
        if (dv.y >= lo && dv.y < hi) { int old = atomicSub(&dg[dv.y], 1); srt[of[dv.y] + old - 1] = sv.y; }
        if (dv.z >= lo && dv.z < hi) { int old = atomicSub(&dg[dv.z], 1); srt[of[dv.z] + old - 1] = sv.z; }
        if (dv.w >= lo && dv.w < hi) { int old = atomicSub(&dg[dv.w], 1); srt[of[dv.w] + old - 1] = sv.w; }
    }
}

// ================= weight prep: fp32 -> bf16 MFMA B-fragment layout =================
__global__ __launch_bounds__(256) void k_prep(const float* __restrict__ We, const float* __restrict__ Wc,
                                              const float* __restrict__ Wd, const float* __restrict__ Ws,
                                              u16* __restrict__ wbe, u16* __restrict__ wbc,
                                              u16* __restrict__ wbd, u16* __restrict__ wbs) {
    int t = blockIdx.x * 256 + threadIdx.x;
    if (t >= 11776) return;
    bf16x8 val;
    u16* dst;
    if (t < 6144) {                       // enc: per m, 8 nt x 4 ks x 64 lanes, K=128, N=128
        int m = t >> 11, r = t & 2047;
        int nt = r >> 8, ks = (r >> 6) & 3, lane = r & 63;
        int n = nt * 16 + (lane & 15), h = n >> 6, o = n & 63;
        int kb = ks * 32 + (lane >> 4) * 8;
        const float* w = We + ((size_t)(m * 2 + h) * 128) * 64;
#pragma unroll
        for (int j = 0; j < 8; j++) val[j] = (short)f2b(w[(size_t)(kb + j) * 64 + o]);
        dst = wbe + ((size_t)m * 2048 + r) * 8;
    } else if (t < 9216) {                // conv: per m, 8 nt x 2 ks, K=64, N=128 (head-blockdiag)
        int u = t - 6144;
        int m = u >> 10, r = u & 1023;
        int nt = r >> 7, ks = (r >> 6) & 1, lane = r & 63;
        int h = nt >> 2, o = (nt & 3) * 16 + (lane & 15);
        int kb = ks * 32 + (lane >> 4) * 8;
        const float* w = Wc + ((size_t)(m * 2 + h) * 64) * 64;
#pragma unroll
        for (int j = 0; j < 8; j++) val[j] = (short)f2b(w[(size_t)(kb + j) * 64 + o]);
        dst = wbc + ((size_t)m * 1024 + r) * 8;
    } else if (t < 10752) {               // dec: per m, 4 nt x 2 ks, K=64, N=64 (head-blockdiag)
        int u = t - 9216;
        int m = u >> 9, r = u & 511;
        int nt = r >> 7, ks = (r >> 6) & 1, lane = r & 63;
        int h = nt >> 1, o = (nt & 1) * 16 + (lane & 15);
        int kb = ks * 32 + (lane >> 4) * 8;
        const float* w = Wd + ((size_t)(m * 2 + h) * 64) * 32;
#pragma unroll
        for (int j = 0; j < 8; j++) val[j] = (short)f2b(w[(size_t)(kb + j) * 32 + o]);
        dst = wbd + ((size_t)m * 512 + r) * 8;
    } else {                              // W_s: 8 nt x 2 ks, K=64, N=128
        int r = t - 10752;
        int nt = r >> 7, ks = (r >> 6) & 1, lane = r & 63;
        int n = nt * 16 + (lane & 15);
        int kb = ks * 32 + (lane >> 4) * 8;
#pragma unroll
        for (int j = 0; j < 8; j++) val[j] = (short)f2b(Ws[(size_t)(kb + j) * 128 + n]);
        dst = wbs + (size_t)r * 8;
    }
    *(bf16x8*)dst = val;
}

// ================= fused enc+conv: xw = (lrelu(x@We+be)) @ Wc, h tile via LDS =================
#define HLS 133   // fp32 row stride: 5*r mod 32 -> 2 lanes/bank (free)
__global__ __launch_bounds__(256) void k_encconv(const float* __restrict__ x,
                                                 const u16* __restrict__ wbe,
                                                 const float* __restrict__ be,
                                                 const u16* __restrict__ wbc,
                                                 u16* __restrict__ xw) {
    __shared__ float hl[64 * HLS];
    const int tid = threadIdx.x, lane = tid & 63, wave = tid >> 6;
    const int quad = lane >> 4, c16 = lane & 15;
    const int row = blockIdx.x * 64 + wave * 16 + c16;
    const bool ok = row < NN;
    const bf16x8* wbE = (const bf16x8*)wbe;
    f32x4 zero = {0.f, 0.f, 0.f, 0.f};
    f32x4 acc[8];
#pragma unroll
    for (int nt = 0; nt < 8; nt++) acc[nt] = zero;
#pragma unroll
    for (int ks = 0; ks < 4; ks++) {
        bf16x8 a = {0, 0, 0, 0, 0, 0, 0, 0};
        if (ok) {
            const float* xp = x + (size_t)row * 128 + ks * 32 + quad * 8;
            float4 xa = *(const float4*)xp;
            float4 xb = *(const float4*)(xp + 4);
            a[0] = (short)f2b(xa.x); a[1] = (short)f2b(xa.y);
            a[2] = (short)f2b(xa.z); a[3] = (short)f2b(xa.w);
            a[4] = (short)f2b(xb.x); a[5] = (short)f2b(xb.y);
            a[6] = (short)f2b(xb.z); a[7] = (short)f2b(xb.w);
        }
#pragma unroll
        for (int nt = 0; nt < 8; nt++)
            acc[nt] = __builtin_amdgcn_mfma_f32_16x16x32_bf16(a, wbE[(nt * 4 + ks) * 64 + lane], acc[nt], 0, 0, 0);
    }
    // h epilogue -> LDS (fp32, lrelu+bias applied; OOB rows -> 0)
    const int rbl = wave * 16 + quad * 4;
#pragma unroll
    for (int nt = 0; nt < 8; nt++) {
        int col = nt * 16 + c16, hh = col >> 6, o = col & 63;
        float bias = be[hh * 64 + o];
#pragma unroll
        for (int j = 0; j < 4; j++) {
            int rl = rbl + j;
            int rg = blockIdx.x * 64 + rl;
            hl[rl * HLS + col] = (rg < NN) ? lrelu(acc[nt][j] + bias) : 0.f;
        }
    }
    __syncthreads();
    // conv from LDS h tile
    const bf16x8* wbC = (const bf16x8*)wbc;
    f32x4 cacc[8];
#pragma unroll
    for (int nt = 0; nt < 8; nt++) cacc[nt] = zero;
    const int rl = wave * 16 + c16;
#pragma unroll
    for (int ks = 0; ks < 2; ks++) {
        bf16x8 a0, a1;
        const float* hp = &hl[rl * HLS + ks * 32 + quad * 8];
#pragma unroll
        for (int j = 0; j < 8; j++) { a0[j] = (short)f2b(hp[j]); a1[j] = (short)f2b(hp[64 + j]); }
#pragma unroll
        for (int nt = 0; nt < 8; nt++)
            cacc[nt] = __builtin_amdgcn_mfma_f32_16x16x32_bf16(nt < 4 ? a0 : a1, wbC[(nt * 2 + ks) * 64 + lane], cacc[nt], 0, 0, 0);
    }
#pragma unroll
    for (int nt = 0; nt < 8; nt++) {
        int col = nt * 16 + c16;
#pragma unroll
        for (int j = 0; j < 4; j++) {
            int r = blockIdx.x * 64 + rbl + j;
            if (r < NN) xw[(size_t)r * 128 + col] = f2b(cacc[nt][j]);
        }
    }
}

// ================= gather: gg[dst] = rs[dst] * sum_src rs[src]*xw[src] =================
__global__ __launch_bounds__(256) void k_gather(const int* __restrict__ sorted,
                                                const int* __restrict__ ofs,
                                                const float* __restrict__ rs,
                                                const u16* __restrict__ xw,
                                                u16* __restrict__ gg) {
    const int tid = threadIdx.x;
    const int dst = blockIdx.x * 4 + (tid >> 6);
    if (dst >= NN) return;
    const int lane = tid & 63, p = lane >> 5, c = lane & 31;
    int beg = ofs[dst], end = ofs[dst + 1];
    float a0 = 0.f, a1 = 0.f, a2 = 0.f, a3 = 0.f;
    for (int j = beg + p; j < end; j += 2) {
        int s = sorted[j];
        float cf = rs[s];
        ushort4 v = *(const ushort4*)&xw[(size_t)s * 128 + c * 4];
        a0 = fmaf(cf, b2f(v.x), a0);
        a1 = fmaf(cf, b2f(v.y), a1);
        a2 = fmaf(cf, b2f(v.z), a2);
        a3 = fmaf(cf, b2f(v.w), a3);
    }
    a0 += __shfl_down(a0, 32);
    a1 += __shfl_down(a1, 32);
    a2 += __shfl_down(a2, 32);
    a3 += __shfl_down(a3, 32);
    if (p == 0) {
        float rsd = rs[dst];
        ushort4 o;
        o.x = f2b(a0 * rsd); o.y = f2b(a1 * rsd);
        o.z = f2b(a2 * rsd); o.w = f2b(a3 * rsd);
        *(ushort4*)&gg[(size_t)dst * 128 + c * 4] = o;
    }
}

// ================= post+score =================
__global__ __launch_bounds__(256) void k_post(const u16* __restrict__ gg,
                                              const u16* __restrict__ xw,
                                              const float* __restrict__ rs,
                                              const float* __restrict__ bconv,
                                              const u16* __restrict__ wbd,
                                              const float* __restrict__ bdec,
                                              const u16* __restrict__ wbs,
                                              const float* __restrict__ bs,
                                              const float* __restrict__ qv,
                                              float* __restrict__ z,
                                              float* __restrict__ score, int m) {
    __shared__ float zl[64 * 68];
    const int tid = threadIdx.x, lane = tid & 63, wave = tid >> 6;
    const int quad = lane >> 4, c16 = lane & 15;
    const int row = blockIdx.x * 64 + wave * 16 + c16;
    const bool ok = row < NN;
    float rs2 = 0.f;
    if (ok) { float t = rs[row]; rs2 = t * t; }
    const bf16x8* wd = (const bf16x8*)wbd;
    f32x4 acc[4];
    f32x4 zero = {0.f, 0.f, 0.f, 0.f};
#pragma unroll
    for (int nt = 0; nt < 4; nt++) acc[nt] = zero;
#pragma unroll
    for (int ks = 0; ks < 2; ks++) {
        bf16x8 a0 = {0,0,0,0,0,0,0,0}, a1 = {0,0,0,0,0,0,0,0};
        if (ok) {
            int k0 = ks * 32 + quad * 8;
            const u16* gp0 = &gg[(size_t)row * 128 + k0];
            const u16* xp0 = &xw[(size_t)row * 128 + k0];
            const u16* gp1 = gp0 + 64;
            const u16* xp1 = xp0 + 64;
#pragma unroll
            for (int j = 0; j < 8; j++) {
                float v0 = lrelu(fmaf(b2f(xp0[j]), rs2, b2f(gp0[j])) + bconv[k0 + j]);
                float v1 = lrelu(fmaf(b2f(xp1[j]), rs2, b2f(gp1[j])) + bconv[64 + k0 + j]);
                a0[j] = (short)f2b(v0);
                a1[j] = (short)f2b(v1);
            }
        }
#pragma unroll
        for (int nt = 0; nt < 4; nt++)
            acc[nt] = __builtin_amdgcn_mfma_f32_16x16x32_bf16(nt < 2 ? a0 : a1, wd[(nt * 2 + ks) * 64 + lane], acc[nt], 0, 0, 0);
    }
    const int rbl = wave * 16 + quad * 4;
#pragma unroll
    for (int nt = 0; nt < 4; nt++) {
        int col = nt * 16 + c16, hh = col >> 5, o = col & 31;
        float bias = bdec[hh * 32 + o];
#pragma unroll
        for (int j = 0; j < 4; j++) {
            int rl = rbl + j;
            int rg = blockIdx.x * 64 + rl;
            zl[rl * 68 + col] = (rg < NN) ? (acc[nt][j] + bias) : 0.f;
        }
    }
    __syncthreads();
    {
        int rl = tid >> 2, cq = tid & 3;
        int rg = blockIdx.x * 64 + rl;
        if (rg < NN) {
#pragma unroll
            for (int i = 0; i < 4; i++) {
                int c4 = (cq * 4 + i) * 4;
                *(float4*)&z[(size_t)rg * 64 + c4] = *(const float4*)&zl[rl * 68 + c4];
            }
        }
    }
    const bf16x8* wsb = (const bf16x8*)wbs;
    f32x4 sa[8];
#pragma unroll
    for (int nt = 0; nt < 8; nt++) sa[nt] = zero;
#pragma unroll
    for (int ks = 0; ks < 2; ks++) {
        bf16x8 a;
        const float* zp = &zl[(wave * 16 + c16) * 68 + ks * 32 + quad * 8];
#pragma unroll
        for (int j = 0; j < 8; j++) a[j] = (short)f2b(zp[j]);
#pragma unroll
        for (int nt = 0; nt < 8; nt++)
            sa[nt] = __builtin_amdgcn_mfma_f32_16x16x32_bf16(a, wsb[(nt * 2 + ks) * 64 + lane], sa[nt], 0, 0, 0);
    }
    float s = 0.f;
#pragma unroll
    for (int nt = 0; nt < 8; nt++) {
        int col = nt * 16 + c16;
        float qc = qv[col], bb = bs[col];
#pragma unroll
        for (int j = 0; j < 4; j++) {
            int rg = blockIdx.x * 64 + rbl + j;
            if (rg < NN) s += fast_tanh(sa[nt][j] + bb) * qc;
        }
    }
#pragma unroll
    for (int off = 1; off < 64; off <<= 1) s += __shfl_xor(s, off);
    if (lane == 0) atomicAdd(&score[m], s);
}

// ================= beta =================
__global__ void k_beta(const float* __restrict__ score, float* __restrict__ beta_ws,
                       float* __restrict__ out) {
    if (threadIdx.x == 0) {
        float s0 = score[0] / (float)NN, s1 = score[1] / (float)NN, s2 = score[2] / (float)NN;
        float mx = fmaxf(s0, fmaxf(s1, s2));
        float e0 = expf(s0 - mx), e1 = expf(s1 - mx), e2 = expf(s2 - mx);
        float inv = 1.f / (e0 + e1 + e2);
        beta_ws[0] = e0 * inv; beta_ws[1] = e1 * inv; beta_ws[2] = e2 * inv;
        out[800000] = e0 * inv; out[800001] = e1 * inv; out[800002] = e2 * inv;
    }
}

// ================= output =================
__global__ __launch_bounds__(256) void k_out(const float* __restrict__ z,
                                             const float* __restrict__ beta,
                                             const float* __restrict__ Wo,
                                             const float* __restrict__ bo,
                                             float* __restrict__ out) {
    __shared__ float Zt[64 * 68];
    __shared__ float Wl[64 * 16];
    __shared__ float bl[16];
    const int tid = threadIdx.x, nbase = blockIdx.x * 64;
    float b0 = beta[0], b1 = beta[1], b2 = beta[2];
    for (int qq = tid; qq < 64 * 16; qq += 256) {
        int node = qq >> 4, k4 = qq & 15;
        int ng = nbase + node;
        float4 v = make_float4(0.f, 0.f, 0.f, 0.f);
        if (ng < NN) {
            float4 z0 = *(const float4*)&z[((size_t)0 * NN + ng) * 64 + k4 * 4];
            float4 z1 = *(const float4*)&z[((size_t)1 * NN + ng) * 64 + k4 * 4];
            float4 z2 = *(const float4*)&z[((size_t)2 * NN + ng) * 64 + k4 * 4];
            v.x = b0 * z0.x + b1 * z1.x + b2 * z2.x;
            v.y = b0 * z0.y + b1 * z1.y + b2 * z2.y;
            v.z = b0 * z0.z + b1 * z1.z + b2 * z2.z;
            v.w = b0 * z0.w + b1 * z1.w + b2 * z2.w;
        }
        *(float4*)&Zt[node * 68 + k4 * 4] = v;
    }
    for (int qq = tid; qq < 64 * 16 / 4; qq += 256)
        ((float4*)Wl)[qq] = ((const float4*)Wo)[qq];
    if (tid < 16) bl[tid] = bo[tid];
    __syncthreads();

    const int node = tid >> 2, cg = tid & 3;
    float4 a = make_float4(bl[cg * 4 + 0], bl[cg * 4 + 1], bl[cg * 4 + 2], bl[cg * 4 + 3]);
    for (int k = 0; k < 64; k++) {
        float zv = Zt[node * 68 + k];
        float4 w = *(const float4*)&Wl[k * 16 + cg * 4];
        a.x = fmaf(zv, w.x, a.x);
        a.y = fmaf(zv, w.y, a.y);
        a.z = fmaf(zv, w.z, a.z);
        a.w = fmaf(zv, w.w, a.w);
    }
    float mx = fmaxf(fmaxf(a.x, a.y), fmaxf(a.z, a.w));
    mx = fmaxf(mx, __shfl_xor(mx, 1));
    mx = fmaxf(mx, __shfl_xor(mx, 2));
    float sm = expf(a.x - mx) + expf(a.y - mx) + expf(a.z - mx) + expf(a.w - mx);
    sm += __shfl_xor(sm, 1);
    sm += __shfl_xor(sm, 2);
    float lse = mx + logf(sm);
    int ng = nbase + node;
    if (ng < NN) {
        float4 r = make_float4(a.x - lse, a.y - lse, a.z - lse, a.w - lse);
        *(float4*)&out[(size_t)ng * 16 + cg * 4] = r;
    }
}

extern "C" void kernel_launch(void* const* d_in, const int* in_sizes, int n_in,
                              void* d_out, int out_size, void* d_ws, size_t ws_size,
                              hipStream_t stream) {
    const float* x      = (const float*)d_in[0];
    const int*   ei     = (const int*)d_in[1];
    const float* W_enc  = (const float*)d_in[2];
    const float* b_enc  = (const float*)d_in[3];
    const float* W_conv = (const float*)d_in[4];
    const float* b_conv = (const float*)d_in[5];
    const float* W_dec  = (const float*)d_in[6];
    const float* b_dec  = (const float*)d_in[7];
    const float* W_s    = (const float*)d_in[8];
    const float* b_s    = (const float*)d_in[9];
    const float* qv     = (const float*)d_in[10];
    const float* W_o    = (const float*)d_in[11];
    const float* b_o    = (const float*)d_in[12];
    float* out = (float*)d_out;

    char* ws = (char*)d_ws;
    size_t off = 0;
    auto alloc = [&](size_t bytes) -> char* {
        char* p = ws + off;
        off = (off + bytes + 255) & ~(size_t)255;
        return p;
    };
    int*   deg_i   = (int*)alloc((size_t)MM * NN * 4);
    int*   row_ofs = (int*)alloc((size_t)MM * (NN + 1) * 4);
    float* rs      = (float*)alloc((size_t)MM * NN * 4);
    int*   sorted  = (int*)alloc((size_t)MM * EE * 4);
    int*   bsum    = (int*)alloc((size_t)MM * SB * 4);
    float* score   = (float*)alloc(64);
    float* beta_ws = (float*)alloc(64);
    u16*   wbe     = (u16*)alloc((size_t)MM * 2048 * 8 * 2);
    u16*   wbc     = (u16*)alloc((size_t)MM * 1024 * 8 * 2);
    u16*   wbd     = (u16*)alloc((size_t)MM * 512 * 8 * 2);
    u16*   wbs     = (u16*)alloc((size_t)1024 * 8 * 2);
    u16*   xw_buf  = (u16*)alloc((size_t)NN * 128 * 2);      // per-m, reused
    u16*   gg_buf  = (u16*)alloc((size_t)NN * 128 * 2);      // per-m, reused
    float* z_buf   = (float*)alloc((size_t)MM * NN * 64 * 4);

    hipMemsetAsync(deg_i, 0, (size_t)MM * NN * 4, stream);
    hipMemsetAsync(score, 0, 16, stream);

    dim3 gpart(NPART * NSLICE, MM);
    dim3 gscan(SB, MM);
    k_deg<<<gpart, 256, 0, stream>>>(ei, deg_i);
    k_scan1<<<gscan, 256, 0, stream>>>(deg_i, bsum);
    k_scan2<<<1, 256, 0, stream>>>(bsum);
    k_scan3<<<gscan, 256, 0, stream>>>(deg_i, bsum, row_ofs, rs);
    k_fill<<<gpart, 256, 0, stream>>>(ei, deg_i, row_ofs, sorted);
    k_prep<<<46, 256, 0, stream>>>(W_enc, W_conv, W_dec, W_s, wbe, wbc, wbd, wbs);

    const int GB = (NN + 63) / 64;   // 782
    for (int m = 0; m < MM; m++) {
        k_encconv<<<GB, 256, 0, stream>>>(x, wbe + (size_t)m * 2048 * 8,
                                          b_enc + (size_t)m * 2 * 64,
                                          wbc + (size_t)m * 1024 * 8, xw_buf);
        k_gather<<<(NN + 3) / 4, 256, 0, stream>>>(sorted + (size_t)m * EE,
                                                   row_ofs + (size_t)m * (NN + 1),
                                                   rs + (size_t)m * NN, xw_buf, gg_buf);
        k_post<<<GB, 256, 0, stream>>>(gg_buf, xw_buf, rs + (size_t)m * NN,
                                       b_conv + (size_t)m * 2 * 64,
                                       wbd + (size_t)m * 512 * 8,
                                       b_dec + (size_t)m * 2 * 32,
                                       wbs, b_s, qv,
                                       z_buf + (size_t)m * NN * 64, score, m);
    }
    k_beta<<<1, 64, 0, stream>>>(score, beta_ws, out);
    k_out<<<GB, 256, 0, stream>>>(z_buf, beta_ws, W_o, b_o, out);
}